// Round 8
// baseline (525.552 us; speedup 1.0000x reference)
//
#include <hip/hip_runtime.h>
#include <cstdint>
#include <cstddef>

#define B_ 4
#define N_ 2048
#define D_ 384
#define H_ 8
#define HD_ 48
#define G_ 512
#define K_ 8
#define HID_ 1536
#define FIN_ 515
#define FINP_ 576
#define M_ (B_*N_)
#define QSCALE 0.20823512f   // 48^-0.5 * log2(e)  -> softmax in exp2 domain

typedef unsigned short u16;
typedef __attribute__((ext_vector_type(8))) short bf16x8;
typedef __attribute__((ext_vector_type(4))) float f32x4;

// direct HBM->LDS DMA, 16B per lane, LDS dest = wave-uniform base + lane*16
#define GLOAD16(gp, lp) __builtin_amdgcn_global_load_lds( \
    (const __attribute__((address_space(1))) void*)(gp), \
    (__attribute__((address_space(3))) void*)(lp), 16, 0, 0)

__device__ __forceinline__ u16 f2bf(float x){
  unsigned u = __builtin_bit_cast(unsigned, x);
  unsigned r = (u + 0x7fffu + ((u >> 16) & 1u)) >> 16;
  return (u16)r;
}
__device__ __forceinline__ float bf2f(u16 v){
  unsigned u = ((unsigned)v) << 16;
  return __builtin_bit_cast(float, u);
}
__device__ __forceinline__ float exp2_hw(float x){
  float r;
  asm("v_exp_f32 %0, %1" : "=v"(r) : "v"(x));
  return r;
}
__device__ __forceinline__ float gelu_f(float x){
  return 0.5f*x*(1.f + erff(x*0.70710678118654752f));
}

// ---------------- transpose [B,R,C] -> [B,C,R] (f32) ----------------
__global__ __launch_bounds__(256) void transpose_k(const float* __restrict__ in,
    float* __restrict__ out, int R, int C){
  __shared__ float tile[32][33];
  int b = blockIdx.z;
  int c0 = blockIdx.x<<5, r0 = blockIdx.y<<5;
  const float* ip = in + (size_t)b*R*C;
  float* op = out + (size_t)b*R*C;
  int tx = threadIdx.x, ty = threadIdx.y;
  #pragma unroll
  for (int i = ty; i < 32; i += 8)
    tile[i][tx] = ip[(size_t)(r0+i)*C + c0 + tx];
  __syncthreads();
  #pragma unroll
  for (int i = ty; i < 32; i += 8)
    op[(size_t)(c0+i)*R + r0 + tx] = tile[tx][i];
}

// ---------------- merged weight transpose+convert ----------------
// Np = padded output-row count: rows [Nd, Np) are written as ZEROS (uninit
// workspace may hold NaN; NaN*0=NaN would poison padded-K gemms).
struct WJob { const float* src; u16* dst; int Kd, Nd, Kp, diff, Np, nbx, blk0; };
struct WJobs { WJob j[16]; };

__global__ __launch_bounds__(256) void wtconv_all(WJobs J){
  int b = blockIdx.x, ji = 0;
  #pragma unroll
  for (int i=1;i<16;i++) if (b >= J.j[i].blk0) ji = i;
  WJob jb = J.j[ji];
  int local = b - jb.blk0;
  int bx = local % jb.nbx, by = local / jb.nbx;
  __shared__ float tile[32][33];
  int k0 = bx<<5, n0 = by<<5;
  int tx = threadIdx.x, ty = threadIdx.y;
  #pragma unroll
  for (int i = ty; i < 32; i += 8){
    int k = k0+i, n = n0+tx;
    float v = 0.f;
    if (k < jb.Kd && n < jb.Nd){
      v = jb.src[(size_t)k*jb.Nd + n];
      if (jb.diff) v = jb.src[(size_t)(k+jb.diff)*jb.Nd + n] - v;
    }
    tile[i][tx] = v;
  }
  __syncthreads();
  #pragma unroll
  for (int i = ty; i < 32; i += 8){
    int n = n0+i, k = k0+tx;
    if (n < jb.Np && k < jb.Kp) jb.dst[(size_t)n*jb.Kp + k] = f2bf(tile[tx][i]);
  }
}

// ---------------- weight-product fold: W[n][k] = (pw @ mwt_top)[k][n], bias ----
struct WP { const float *pw, *mwt, *pb, *mb2; u16* W; float* Bo; };
__global__ __launch_bounds__(256) void wprod_k(WP a, WP b){
  WP w = blockIdx.y ? b : a;
  int idx = blockIdx.x*256 + threadIdx.x;
  if (idx >= 385*384) return;
  int n = idx % 384, kk = idx / 384;      // kk: 0..384 (384 = bias row)
  float acc = 0.f;
  if (kk < 384){
    for (int j=0;j<384;j++) acc += w.pw[(size_t)kk*384+j] * w.mwt[(size_t)j*384+n];
    w.W[(size_t)n*768 + kk] = f2bf(acc);
  } else {
    for (int j=0;j<384;j++) acc += w.pb[j] * w.mwt[(size_t)j*384+n];
    w.Bo[n] = acc + w.mb2[n];
  }
}

// ---------------- concat-bias fill ----------------
__global__ __launch_bounds__(256) void biasfill_k(const float* __restrict__ knnb,
    const float* __restrict__ knnxb, float* __restrict__ bws){
  int i = blockIdx.x*256 + threadIdx.x;
  if (i < 2688){
    float v = 0.f;
    if (i >= 1536 && i < 1920) v = knnb[i-1536];
    else if (i >= 2304) v = knnxb[i-2304];
    bws[i] = v;
  }
}

// ---------------- LayerNorm core ----------------
__device__ __forceinline__ void ln_body(const float* xr, const float* g,
    const float* bta, u16* yr, float* sbuf, int t){
  float v0 = xr[t], v1 = xr[t+128], v2 = xr[t+256];
  float s = v0+v1+v2;
  #pragma unroll
  for (int off=32; off>0; off>>=1) s += __shfl_down(s, off, 64);
  int lane = t & 63, w = t >> 6;
  if (lane==0) sbuf[w] = s;
  __syncthreads();
  float mean = (sbuf[0]+sbuf[1]) * (1.f/(float)D_);
  float d0 = v0-mean, d1 = v1-mean, d2 = v2-mean;
  float s2 = d0*d0 + d1*d1 + d2*d2;
  #pragma unroll
  for (int off=32; off>0; off>>=1) s2 += __shfl_down(s2, off, 64);
  __syncthreads();
  if (lane==0) sbuf[w] = s2;
  __syncthreads();
  float inv = rsqrtf((sbuf[0]+sbuf[1])*(1.f/(float)D_) + 1e-5f);
  yr[t]     = f2bf(d0*inv*g[t]     + bta[t]);
  yr[t+128] = f2bf(d1*inv*g[t+128] + bta[t+128]);
  yr[t+256] = f2bf(d2*inv*g[t+256] + bta[t+256]);
}

__global__ __launch_bounds__(128) void ln_bf(const float* __restrict__ x,
    const float* __restrict__ g, const float* __restrict__ bta, u16* __restrict__ y){
  __shared__ float sbuf[2];
  int row = blockIdx.x;
  ln_body(x + (size_t)row*D_, g, bta, y + (size_t)row*D_, sbuf, threadIdx.x);
}

__global__ __launch_bounds__(128) void ln2_bf(const float* __restrict__ x0,
    const float* __restrict__ g0, const float* __restrict__ b0, u16* __restrict__ y0,
    const float* __restrict__ x1, const float* __restrict__ g1,
    const float* __restrict__ b1, u16* __restrict__ y1){
  __shared__ float sbuf[2];
  int row = blockIdx.x;
  if (row < M_)
    ln_body(x0 + (size_t)row*D_, g0, b0, y0 + (size_t)row*D_, sbuf, threadIdx.x);
  else {
    row -= M_;
    ln_body(x1 + (size_t)row*D_, g1, b1, y1 + (size_t)row*D_, sbuf, threadIdx.x);
  }
}

// ---------------- MFMA GEMM, 512 thr, split-K x2 (round-6 version) ----------
// BM=128 BN=64, BK=64 staged (32 per K-group). Used for N=384 gemms where
// BN=128 would halve grid occupancy. global_load_lds staging, single buffer.
// REQUIRES: Kd multiple of 64, A/W rows fully allocated+zero-padded.
template<int ACT, int OUTBF, int ACCUM, int HASBIAS, int SCALEQ>
__global__ __launch_bounds__(512) void gemm8(const u16* __restrict__ A, int lda,
    const u16* __restrict__ Wt, int ldw, const float* __restrict__ bias,
    float* __restrict__ Cf, u16* __restrict__ Cb, int ldc, int Kd, int Nd, int Npad){
  __shared__ char Lmem[33280];                 // max(192*64*2, 128*65*4)
  u16* As = (u16*)Lmem;                        // [128][64], row 128B = 8 slots
  u16* Bs = As + 128*64;                       // [64][64]
  float* cred = (float*)Lmem;                  // [128][65] f32 (after K-loop)
  const int t = threadIdx.x;
  const int wv = t>>6, l = t&63;
  const int kg = wv>>2, wq = wv&3;
  const int wm = wq&1, wn = wq>>1;
  const int lr = l&15, ls = l>>4;
  const int bm = blockIdx.y<<7, bn = blockIdx.x<<6;
  f32x4 z4 = {0.f,0.f,0.f,0.f};
  f32x4 acc[4][2];
  #pragma unroll
  for (int mi=0;mi<4;mi++){ acc[mi][0]=z4; acc[mi][1]=z4; }
  // per-lane source offsets (elements), constant across K-steps
  int ago[2];
  #pragma unroll
  for (int i=0;i<2;i++){
    int g = t + (i<<9);
    int row = g>>3, slot = g&7;
    ago[i] = row*lda + ((slot ^ (row&7))<<3);
  }
  int bgo;
  {
    int row = t>>3, slot = t&7;
    bgo = row*ldw + ((slot ^ (row&7))<<3);
  }
  const u16* Abase = A + (size_t)bm*lda;
  const u16* Bbase = Wt + (size_t)bn*ldw;
  for (int k0=0; k0<Kd; k0+=64){
    #pragma unroll
    for (int i=0;i<2;i++)
      GLOAD16(Abase + k0 + ago[i], (char*)As + ((t + (i<<9))<<4));
    GLOAD16(Bbase + k0 + bgo, (char*)Bs + (t<<4));
    __syncthreads();
    bf16x8 af[4], bfr[2];
    #pragma unroll
    for (int mi=0;mi<4;mi++){
      int row = wm*64 + mi*16 + lr;
      int ss = (kg*4 + ls) ^ (row&7);
      af[mi] = *reinterpret_cast<bf16x8*>((char*)As + row*128 + ss*16);
    }
    #pragma unroll
    for (int ni=0;ni<2;ni++){
      int row = wn*32 + ni*16 + lr;
      int ss = (kg*4 + ls) ^ (row&7);
      bfr[ni] = *reinterpret_cast<bf16x8*>((char*)Bs + row*128 + ss*16);
    }
    #pragma unroll
    for (int mi=0;mi<4;mi++)
      #pragma unroll
      for (int ni=0;ni<2;ni++)
        acc[mi][ni] = __builtin_amdgcn_mfma_f32_16x16x32_bf16(af[mi], bfr[ni], acc[mi][ni], 0,0,0);
    __syncthreads();
  }
  // split-K reduce: group1 -> LDS, group0 adds + epilogue
  if (kg == 1){
    #pragma unroll
    for (int mi=0;mi<4;mi++)
      #pragma unroll
      for (int ni=0;ni<2;ni++)
        #pragma unroll
        for (int r=0;r<4;r++){
          int row = wm*64 + mi*16 + ls*4 + r;
          int col = wn*32 + ni*16 + lr;
          cred[row*65 + col] = acc[mi][ni][r];
        }
  }
  __syncthreads();
  if (kg == 0){
    #pragma unroll
    for (int mi=0;mi<4;mi++){
      #pragma unroll
      for (int ni=0;ni<2;ni++){
        #pragma unroll
        for (int r=0;r<4;r++){
          int rl = wm*64 + mi*16 + ls*4 + r;
          int cl = wn*32 + ni*16 + lr;
          int row = bm + rl, col = bn + cl;
          float v = acc[mi][ni][r] + cred[rl*65 + cl];
          if (col < Nd){
            if (SCALEQ && col < 384) v *= QSCALE;
            if (HASBIAS) v += bias[col];
            if (ACT) v = gelu_f(v);
            if (OUTBF) Cb[(size_t)row*ldc + col] = f2bf(v);
            else if (ACCUM) Cf[(size_t)row*ldc + col] += v;
            else Cf[(size_t)row*ldc + col] = v;
          } else if (OUTBF && col < Npad){
            Cb[(size_t)row*ldc + col] = 0;
          }
        }
      }
    }
  }
}

// ---------------- MFMA GEMM, 256 thr, BM=128 BN=128, 64x64 wave tile --------
// 4 waves 2x2, acc[4][4], no split-K (K handled as 2 sequential slots per
// BK=64 step, taking gemm8's kg role as ks). 32 MFMA : 16 ds_read_b128 per
// wave per K-step (ratio 2.0 vs gemm8's 1.33) -- LDS-pipe relief.
// REQUIRES: Kd multiple of 64; A rows and W rows [bn, bn+128) fully
// allocated+zero-padded; N extent covered by grid*128 (epilogue bounds
// writes by Nd/Npad).
template<int ACT, int OUTBF, int HASBIAS, int SCALEQ>
__global__ __launch_bounds__(256) void gemm4w(const u16* __restrict__ A, int lda,
    const u16* __restrict__ Wt, int ldw, const float* __restrict__ bias,
    u16* __restrict__ Cb, int ldc, int Kd, int Nd, int Npad){
  __shared__ __align__(16) char Lmem[32768];   // A[128][64] | B[128][64]
  const int t = threadIdx.x;
  const int wv = t>>6, l = t&63;
  const int wr = wv&1, wc = wv>>1;
  const int lr = l&15, ls = l>>4;
  const int bm = blockIdx.y<<7, bn = blockIdx.x<<7;
  f32x4 z4 = {0.f,0.f,0.f,0.f};
  f32x4 acc[4][4];
  #pragma unroll
  for (int mi=0;mi<4;mi++)
    #pragma unroll
    for (int ni=0;ni<4;ni++) acc[mi][ni] = z4;
  // per-lane source offsets (elements), constant across K-steps
  int ago[4], bgo[4];
  #pragma unroll
  for (int i=0;i<4;i++){
    int g = t + (i<<8);
    int row = g>>3, slot = g&7;
    int so = (slot ^ (row&7))<<3;
    ago[i] = row*lda + so;
    bgo[i] = row*ldw + so;
  }
  const u16* Abase = A + (size_t)bm*lda;
  const u16* Bbase = Wt + (size_t)bn*ldw;
  for (int k0=0; k0<Kd; k0+=64){
    #pragma unroll
    for (int i=0;i<4;i++)
      GLOAD16(Abase + k0 + ago[i], Lmem + ((t + (i<<8))<<4));
    #pragma unroll
    for (int i=0;i<4;i++)
      GLOAD16(Bbase + k0 + bgo[i], Lmem + 16384 + ((t + (i<<8))<<4));
    __syncthreads();
    #pragma unroll
    for (int ks=0; ks<2; ks++){
      bf16x8 af[4], bfr[4];
      #pragma unroll
      for (int mi=0;mi<4;mi++){
        int row = wr*64 + mi*16 + lr;
        int ss = (ks*4 + ls) ^ (row&7);
        af[mi] = *reinterpret_cast<bf16x8*>(Lmem + row*128 + ss*16);
      }
      #pragma unroll
      for (int ni=0;ni<4;ni++){
        int row = wc*64 + ni*16 + lr;
        int ss = (ks*4 + ls) ^ (row&7);
        bfr[ni] = *reinterpret_cast<bf16x8*>(Lmem + 16384 + row*128 + ss*16);
      }
      __builtin_amdgcn_s_setprio(1);
      #pragma unroll
      for (int mi=0;mi<4;mi++)
        #pragma unroll
        for (int ni=0;ni<4;ni++)
          acc[mi][ni] = __builtin_amdgcn_mfma_f32_16x16x32_bf16(af[mi], bfr[ni], acc[mi][ni], 0,0,0);
      __builtin_amdgcn_s_setprio(0);
    }
    __syncthreads();
  }
  // epilogue (direct, no split-K reduce)
  #pragma unroll
  for (int mi=0;mi<4;mi++){
    #pragma unroll
    for (int ni=0;ni<4;ni++){
      #pragma unroll
      for (int r=0;r<4;r++){
        int row = bm + wr*64 + mi*16 + ls*4 + r;
        int col = bn + wc*64 + ni*16 + lr;
        float v = acc[mi][ni][r];
        if (col < Nd){
          if (SCALEQ && col < 384) v *= QSCALE;
          if (HASBIAS) v += bias[col];
          if (ACT) v = gelu_f(v);
          Cb[(size_t)row*ldc + col] = f2bf(v);
        } else if (col < Npad){
          Cb[(size_t)row*ldc + col] = 0;
        }
      }
    }
  }
}

// ---------------- V^T builder: Vt[bh][48][N], attn-permuted key order -------
// Within each 128-key tile of row d, 16B slot position s holds slot
// u = s ^ (d&15); slot u = [keys 32*(u>>2)+4*(u&3)+0..3 | same+16].
// This makes the attn V-stage a LINEAR global_load_lds while keeping the
// round-1 (conflict-free, verified) LDS read addressing.
__global__ __launch_bounds__(256) void vt_k(const u16* __restrict__ X, int ld,
                                            u16* __restrict__ Vt){
  __shared__ u16 tl[64][72];
  int bh = blockIdx.y, b = bh>>3, h = bh&7;
  int n0 = blockIdx.x<<6;
  #pragma unroll
  for (int i=0;i<2;i++){
    int g = threadIdx.x + (i<<8);
    if (g < 384){
      int r = g/6, c = (g - r*6)*8;
      *reinterpret_cast<float4*>(&tl[r][c]) =
        *reinterpret_cast<const float4*>(X + (size_t)(b*N_ + n0 + r)*ld + h*HD_ + c);
    }
  }
  __syncthreads();
  #pragma unroll
  for (int i=0;i<2;i++){
    int g = threadIdx.x + (i<<8);
    if (g < 384){
      int d = g % 48, sb = g / 48;
      int hf = (n0>>6)&1;
      int kt0 = n0 & ~127;
      size_t rowb = ((size_t)(bh*HD_+d))*N_ + kt0;
      int kA = hf*64 + sb*8;                 // keys kA..kA+7 (two 4-runs)
      ushort4 va, vb;
      va.x = tl[sb*8+0][d]; va.y = tl[sb*8+1][d];
      va.z = tl[sb*8+2][d]; va.w = tl[sb*8+3][d];
      vb.x = tl[sb*8+4][d]; vb.y = tl[sb*8+5][d];
      vb.z = tl[sb*8+6][d]; vb.w = tl[sb*8+7][d];
      int uA = ((kA>>5)<<2) | ((kA>>2)&3);
      int pA = (((uA ^ (d&15)))<<3) + (((kA>>4)&1)<<2);
      int kB = kA + 4;
      int uB = ((kB>>5)<<2) | ((kB>>2)&3);
      int pB = (((uB ^ (d&15)))<<3) + (((kB>>4)&1)<<2);
      *reinterpret_cast<ushort4*>(Vt + rowb + pA) = va;
      *reinterpret_cast<ushort4*>(Vt + rowb + pB) = vb;
    }
  }
}

// ---------------- MFMA flash attention, KVBLK=128, LDS double-buffer --------
// (round-5 version, equal-best 66-70us band; compute-phase bound)
__global__ __launch_bounds__(256) void attn_mfma(const u16* __restrict__ Qp, int ldq,
    const u16* __restrict__ Kp, int ldk, const u16* __restrict__ Vt,
    u16* __restrict__ O, int ldo){
  __shared__ __align__(16) char KVls[2][28672];   // per buf: K 16384B | V 12288B
  const int t = threadIdx.x, wv = t>>6, l = t&63;
  const int lr = l&15, ls = l>>4;
  const int bh = blockIdx.y, bb = bh>>3, h = bh&7;
  const int q0 = blockIdx.x<<6;
  bf16x8 zf = {0,0,0,0,0,0,0,0};
  f32x4 z4 = {0.f,0.f,0.f,0.f};
  const size_t rowQ = ((size_t)(bb*N_ + q0 + wv*16 + lr))*ldq + h*HD_;
  bf16x8 qa0 = *reinterpret_cast<const bf16x8*>(Qp + rowQ + 8*ls);
  bf16x8 qa1 = (ls < 2) ? *reinterpret_cast<const bf16x8*>(Qp + rowQ + 32 + 8*ls) : zf;
  f32x4 oacc[3] = {z4, z4, z4};
  float mrun = -1.0e30f, lrun = 0.f;

  // per-lane global source offsets (elements); LDS dest is linear in granule
  const u16* Kbase = Kp + (size_t)(bb*N_)*ldk + h*HD_;
  const u16* Vbase = Vt + (size_t)bh*HD_*N_;
  int kgo[4];
  #pragma unroll
  for (int i=0;i<4;i++){
    int g = t + (i<<8);
    int key = g>>3, s = g&7;
    kgo[i] = key*ldk + ((s ^ (key&7))<<3);   // source slot for linear dest
  }
  int vgo[3];
  #pragma unroll
  for (int i=0;i<3;i++){
    int g = t + (i<<8);
    int d = g>>4, s = g&15;
    vgo[i] = d*N_ + (s<<3);                  // Vt already attn-permuted
  }

  auto stage = [&](int kt, char* buf){
    const u16* kp = Kbase + (size_t)kt*128*ldk;
    #pragma unroll
    for (int i=0;i<4;i++)
      GLOAD16(kp + kgo[i], buf + ((t + (i<<8))<<4));
    const u16* vp = Vbase + kt*128;
    #pragma unroll
    for (int i=0;i<3;i++)
      GLOAD16(vp + vgo[i], buf + 16384 + ((t + (i<<8))<<4));
  };

  stage(0, KVls[0]);
  for (int kt = 0; kt < N_/128; kt++){
    char* cbuf = KVls[kt&1];
    if (kt+1 < N_/128){
      stage(kt+1, KVls[(kt+1)&1]);
      asm volatile("s_waitcnt vmcnt(7)" ::: "memory");   // tile-kt landed; kt+1 in flight
    } else {
      asm volatile("s_waitcnt vmcnt(0)" ::: "memory");
    }
    __builtin_amdgcn_sched_barrier(0);
    __builtin_amdgcn_s_barrier();
    __builtin_amdgcn_sched_barrier(0);
    // ---- QK^T (swapped): S^T[key][q], key = sub*16+ls*4+r, q = lr ----
    f32x4 S[8];
    __builtin_amdgcn_s_setprio(1);
    #pragma unroll
    for (int sub=0; sub<8; sub++){
      int krow = sub*16 + lr;
      bf16x8 kb0 = *reinterpret_cast<bf16x8*>(cbuf + krow*128 + ((ls ^ (krow&7))<<4));
      bf16x8 kb1 = *reinterpret_cast<bf16x8*>(cbuf + krow*128 + (((4+ls) ^ (krow&7))<<4));
      f32x4 s = __builtin_amdgcn_mfma_f32_16x16x32_bf16(kb0, qa0, z4, 0,0,0);
      S[sub] = __builtin_amdgcn_mfma_f32_16x16x32_bf16(kb1, qa1, s, 0,0,0);
    }
    __builtin_amdgcn_s_setprio(0);
    // ---- online softmax, row fully lane-local ----
    float tm = fmaxf(fmaxf(fmaxf(S[0][0],S[0][1]), fmaxf(S[0][2],S[0][3])),
                     fmaxf(fmaxf(S[1][0],S[1][1]), fmaxf(S[1][2],S[1][3])));
    #pragma unroll
    for (int sub=2;sub<8;sub++)
      tm = fmaxf(tm, fmaxf(fmaxf(S[sub][0],S[sub][1]), fmaxf(S[sub][2],S[sub][3])));
    if (__all(tm - mrun <= 10.f)){
      // defer-max: keep old max, zero cross-lane traffic
      float ps = 0.f;
      #pragma unroll
      for (int sub=0;sub<8;sub++)
        #pragma unroll
        for (int r=0;r<4;r++){
          float p = exp2_hw(S[sub][r]-mrun);
          S[sub][r] = p; ps += p;
        }
      lrun += ps;
    } else {
      float mx = fmaxf(tm, __shfl_xor(tm, 16, 64));
      mx = fmaxf(mx, __shfl_xor(mx, 32, 64));
      float mnew = fmaxf(mrun, mx);
      float al = exp2_hw(mrun - mnew);
      mrun = mnew;
      float ps = 0.f;
      #pragma unroll
      for (int sub=0;sub<8;sub++)
        #pragma unroll
        for (int r=0;r<4;r++){
          float p = exp2_hw(S[sub][r]-mnew);
          S[sub][r] = p; ps += p;
        }
      lrun = lrun*al + ps;
      #pragma unroll
      for (int r=0;r<4;r++){
        float alq = __shfl(al, ls*4 + r, 64);  // al for q = ls*4+r
        oacc[0][r] *= alq; oacc[1][r] *= alq; oacc[2][r] *= alq;
      }
    }
    // ---- pack P A-fragments in-register (no LDS, no cross-lane) ----
    union PU { unsigned u[4]; bf16x8 v; };
    PU pa[4];
    #pragma unroll
    for (int kb=0;kb<4;kb++){
      asm("v_cvt_pk_bf16_f32 %0, %1, %2" : "=v"(pa[kb].u[0]) : "v"(S[2*kb][0]),   "v"(S[2*kb][1]));
      asm("v_cvt_pk_bf16_f32 %0, %1, %2" : "=v"(pa[kb].u[1]) : "v"(S[2*kb][2]),   "v"(S[2*kb][3]));
      asm("v_cvt_pk_bf16_f32 %0, %1, %2" : "=v"(pa[kb].u[2]) : "v"(S[2*kb+1][0]), "v"(S[2*kb+1][1]));
      asm("v_cvt_pk_bf16_f32 %0, %1, %2" : "=v"(pa[kb].u[3]) : "v"(S[2*kb+1][2]), "v"(S[2*kb+1][3]));
    }
    // ---- PV: permuted k-enumeration on the V side, b128 reads ----
    __builtin_amdgcn_s_setprio(1);
    #pragma unroll
    for (int ni=0;ni<3;ni++){
      int d = ni*16 + lr;
      #pragma unroll
      for (int kb=0;kb<4;kb++){
        bf16x8 vb = *reinterpret_cast<bf16x8*>(cbuf + 16384 + d*256 + ((((kb*4+ls) ^ (d&15)))<<4));
        oacc[ni] = __builtin_amdgcn_mfma_f32_16x16x32_bf16(pa[kb].v, vb, oacc[ni], 0,0,0);
      }
    }
    __builtin_amdgcn_s_setprio(0);
    __builtin_amdgcn_sched_barrier(0);
    __builtin_amdgcn_s_barrier();     // WAR: cbuf is re-staged next iteration
    __builtin_amdgcn_sched_barrier(0);
  }
  // final denom: reduce lane-partials across the 4 lanes of each q-row
  float sden = lrun;
  sden += __shfl_xor(sden, 16, 64);
  sden += __shfl_xor(sden, 32, 64);
  #pragma unroll
  for (int r=0;r<4;r++){
    float dq = __shfl(sden, ls*4 + r, 64);     // denom for q = ls*4+r
    float inv = 1.f / dq;
    size_t orow = (size_t)(bb*N_ + q0 + wv*16 + ls*4 + r);
    #pragma unroll
    for (int ni=0;ni<3;ni++)
      O[orow*ldo + h*HD_ + ni*16 + lr] = f2bf(oacc[ni][r] * inv);
  }
}

// ---------------- knn gather + leaky + max over K ----------------
__global__ __launch_bounds__(384) void gather_max_bf(const u16* __restrict__ P, int ldp,
    const u16* __restrict__ Q2, int ldq2, const int* __restrict__ idx,
    u16* __restrict__ out, int ldo){
  int m = blockIdx.x;
  int d = threadIdx.x;
  int b = m >> 11, n = m & (N_-1);
  float q2 = bf2f(Q2[(size_t)m*ldq2 + d]);
  float mx = -3.0e38f;
  #pragma unroll
  for (int k=0;k<K_;k++){
    int j = idx[((b<<3) + k)*N_ + n];
    float val = bf2f(P[(size_t)j*ldp + d]) + q2;
    val = (val >= 0.f) ? val : 0.2f*val;
    mx = fmaxf(mx, val);
  }
  out[(size_t)m*ldo + d] = f2bf(mx);
}

// ---------------- build v_in [M][576] bf16 (zero-padded) ----------------
__global__ __launch_bounds__(256) void build_v(const float* __restrict__ pos,
    const float* __restrict__ gc, u16* __restrict__ v){
  int m = blockIdx.x;
  int b = m >> 11, n = m & (N_-1);
  for (int c = threadIdx.x; c < FINP_; c += 256){
    float val = 0.f;
    if (c < 3) val = pos[(b*3 + c)*N_ + n];
    else if (c < FIN_) val = gc[(b<<9) + (c-3)];
    v[(size_t)m*FINP_ + c] = f2bf(val);
  }
}

extern "C" void kernel_launch(void* const* d_in, const int* in_sizes, int n_in,
                              void* d_out, int out_size, void* d_ws, size_t ws_size,
                              hipStream_t stream){
  const float* q_in   = (const float*)d_in[0];
  const float* in_pos = (const float*)d_in[1];
  const float* guide  = (const float*)d_in[2];
  const float* n1g = (const float*)d_in[3];
  const float* n1b = (const float*)d_in[4];
  const float* qkv_w = (const float*)d_in[5];
  const float* sa_pw = (const float*)d_in[6];
  const float* sa_pb = (const float*)d_in[7];
  const float* nqg = (const float*)d_in[8];
  const float* nqb = (const float*)d_in[9];
  const float* f1w = (const float*)d_in[10];
  const float* f1b = (const float*)d_in[11];
  const float* f2w = (const float*)d_in[12];
  const float* f2b = (const float*)d_in[13];
  const float* nvg = (const float*)d_in[14];
  const float* nvb = (const float*)d_in[15];
  const float* caqw = (const float*)d_in[16];
  const float* cakw = (const float*)d_in[17];
  const float* cavw = (const float*)d_in[18];
  const float* capw = (const float*)d_in[19];
  const float* capb = (const float*)d_in[20];
  const float* n2g = (const float*)d_in[21];
  const float* n2b = (const float*)d_in[22];
  const float* m1w = (const float*)d_in[23];
  const float* m1b = (const float*)d_in[24];
  const float* m2w = (const float*)d_in[25];
  const float* m2b = (const float*)d_in[26];
  const float* knnw = (const float*)d_in[27];
  const float* knnb = (const float*)d_in[28];
  const float* mw = (const float*)d_in[29];
  const float* mb = (const float*)d_in[30];
  const float* knnxw = (const float*)d_in[31];
  const float* knnxb = (const float*)d_in[32];
  const float* mxw = (const float*)d_in[33];
  const float* mxb = (const float*)d_in[34];
  const int* sidx = (const int*)d_in[35];
  const int* cidx = (const int*)d_in[36];
  float* out = (float*)d_out;

  // ---- workspace ----
  const size_t MD = (size_t)M_*D_;
  float* q_cur = (float*)d_ws;
  float* vbuf  = q_cur + MD;
  u16* R     = (u16*)(vbuf + MD);                      // [M][1920]: X1 | Xq+Xv | hid
  u16* nq_bf = R + (size_t)M_*1920;
  u16* nv_bf = nq_bf + MD;
  u16* cc    = nv_bf + MD;                             // [M][768] = [O | knn_f]
  u16* vin   = cc + (size_t)M_*768;
  u16* e2    = vin + (size_t)M_*FINP_;
  u16* Vt    = e2 + (size_t)M_*FINP_;                  // [32][48][2048]
  u16* wb    = Vt + (size_t)32*HD_*N_;
  u16* W1    = wb;  wb += (size_t)1920*384;
  u16* Wq    = wb;  wb += (size_t)768*384;
  u16* Wv    = wb;  wb += (size_t)1152*384;
  u16* Wfold = wb;  wb += (size_t)384*768;
  u16* Wfoldx= wb;  wb += (size_t)384*768;
  u16* f1T   = wb;  wb += (size_t)640*FINP_;           // 640 rows (zero-padded past 515)
  u16* f2T   = wb;  wb += (size_t)384*FINP_;
  u16* m1T   = wb;  wb += (size_t)1536*384;
  u16* m2T   = wb;  wb += (size_t)384*1536;
  if (((uintptr_t)wb & 3) != 0) wb++;
  float* bias_ws = (float*)wb;                         // 2688 concat + 384 fold + 384 foldx
  const size_t needed = (char*)(bias_ws + 3456) - (char*)d_ws;
  if (ws_size < needed) return;

  u16* X1 = R;
  u16* Xq = R;
  u16* Xv = R + (size_t)M_*768;
  u16* hid = R;

  dim3 tb32(32,8);
  // 1. input transpose
  transpose_k<<<dim3(N_/32, D_/32, B_), tb32, 0, stream>>>(q_in, q_cur, D_, N_);
  // 2. weight conversions (14 jobs)
  WJobs J;
  auto setj = [&](int i, const float* src, u16* dst, int Kd, int Nd, int Kp, int diff, int Np){
    J.j[i].src = src; J.j[i].dst = dst; J.j[i].Kd = Kd; J.j[i].Nd = Nd;
    J.j[i].Kp = Kp; J.j[i].diff = diff; J.j[i].Np = Np;
    J.j[i].nbx = (Kp+31)/32; J.j[i].blk0 = 0;
  };
  setj(0,  qkv_w, W1,                    384, 1152, 384, 0,   1152);
  setj(1,  knnw,  W1 + (size_t)1152*384, 384, 384, 384, 0,    384);
  setj(2,  knnw,  W1 + (size_t)1536*384, 384, 384, 384, 384,  384);
  setj(3,  caqw,  Wq,                    384, 384, 384, 0,    384);
  setj(4,  knnxw, Wq + (size_t)384*384,  384, 384, 384, 384,  384);
  setj(5,  cakw,  Wv,                    384, 384, 384, 0,    384);
  setj(6,  cavw,  Wv + (size_t)384*384,  384, 384, 384, 0,    384);
  setj(7,  knnxw, Wv + (size_t)768*384,  384, 384, 384, 0,    384);
  setj(8,  mw  + (size_t)384*384, Wfold  + 384, 384, 384, 768, 0, 384);   // merge bottom half
  setj(9,  mxw + (size_t)384*384, Wfoldx + 384, 384, 384, 768, 0, 384);   // mergex bottom half
  setj(10, f1w,   f1T, FIN_, FIN_, FINP_, 0, 640);     // rows padded to 640 (zeros)
  setj(11, f2w,   f2T, FIN_, 384, FINP_, 0,  384);
  setj(12, m1w,   m1T, 384, 1536, 384, 0,    1536);
  setj(13, m2w,   m2T, 1536, 384, 1536, 0,   384);
  int tot = 0;
  for (int i=0;i<14;i++){ J.j[i].blk0 = tot; tot += J.j[i].nbx * ((J.j[i].Np+31)/32); }
  J.j[14] = J.j[13]; J.j[14].blk0 = 0x7fffffff; J.j[14].nbx = 1;
  J.j[15] = J.j[14];
  wtconv_all<<<tot, tb32, 0, stream>>>(J);
  // folded weights: Wfold[:384] = sa_pw @ mw_top (k-major), bias = mb + sa_pb @ mw_top
  WP wpa = { sa_pw, mw,  sa_pb, mb,  Wfold,  bias_ws + 2688 };
  WP wpb = { capw,  mxw, capb,  mxb, Wfoldx, bias_ws + 3072 };
  wprod_k<<<dim3(578, 2), 256, 0, stream>>>(wpa, wpb);
  biasfill_k<<<11, 256, 0, stream>>>(knnb, knnxb, bias_ws);
  // 3. norm1
  ln_bf<<<M_, 128, 0, stream>>>(q_cur, n1g, n1b, nq_bf);
  // 4. X1 = nq @ [qkv | knnP | knnQ2diff]  (BN=128, 15x64 grid)
  gemm4w<0,1,1,1><<<dim3(15, 64), 256, 0, stream>>>(nq_bf, 384, W1, 384, bias_ws, X1, 1920, 384, 1920, 1920);
  // 5. self attention: O straight into cc[:, :384]
  vt_k<<<dim3(32, 32), 256, 0, stream>>>(X1 + 768, 1920, Vt);
  attn_mfma<<<dim3(32, 32), 256, 0, stream>>>(X1, 1920, X1 + 384, 1920, Vt, cc, 768);
  gather_max_bf<<<M_, 384, 0, stream>>>(X1 + 1152, 1920, X1 + 1536, 1920, sidx, cc + 384, 768);
  // 6. q_cur += [O | knn_f] @ Wfold + bias_fold
  gemm8<0,0,1,1,0><<<dim3(6, 64), 512, 0, stream>>>(cc, 768, Wfold, 768, bias_ws + 2688, q_cur, nullptr, 384, 768, 384, 384);
  // 7. fuse path -> vbuf  (K padded to 576; vin/f1T/f2T/e2 zero-padded)
  build_v<<<M_, 256, 0, stream>>>(in_pos, guide, vin);
  gemm4w<1,1,1,0><<<dim3(5, 64), 256, 0, stream>>>(vin, FINP_, f1T, FINP_, f1b, e2, FINP_, FINP_, FIN_, FINP_);
  gemm8<0,0,0,1,0><<<dim3(6, 64), 512, 0, stream>>>(e2, FINP_, f2T, FINP_, f2b, vbuf, nullptr, 384, FINP_, 384, 384);
  // 8. both norms, one launch
  ln2_bf<<<2*M_, 128, 0, stream>>>(q_cur, nqg, nqb, nq_bf, vbuf, nvg, nvb, nv_bf);
  // 9. cross projections (BN=128)
  gemm4w<0,1,1,1><<<dim3(6, 64), 256, 0, stream>>>(nq_bf, 384, Wq, 384, bias_ws + 1920, Xq, 768, 384, 768, 768);
  gemm4w<0,1,0,0><<<dim3(9, 64), 256, 0, stream>>>(nv_bf, 384, Wv, 384, nullptr, Xv, 1152, 384, 1152, 1152);
  // 10. cross attention
  vt_k<<<dim3(32, 32), 256, 0, stream>>>(Xv + 384, 1152, Vt);
  attn_mfma<<<dim3(32, 32), 256, 0, stream>>>(Xq, 768, Xv, 1152, Vt, cc, 768);
  gather_max_bf<<<M_, 384, 0, stream>>>(Xv + 768, 1152, Xq + 384, 768, cidx, cc + 384, 768);
  // 11. q_cur += [O | knnx_f] @ Wfoldx + biasx
  gemm8<0,0,1,1,0><<<dim3(6, 64), 512, 0, stream>>>(cc, 768, Wfoldx, 768, bias_ws + 3072, q_cur, nullptr, 384, 768, 384, 384);
  // 12. MLP
  ln_bf<<<M_, 128, 0, stream>>>(q_cur, n2g, n2b, nq_bf);
  gemm4w<1,1,1,0><<<dim3(12, 64), 256, 0, stream>>>(nq_bf, 384, m1T, 384, m1b, hid, 1536, 384, 1536, 1536);
  gemm8<0,0,1,1,0><<<dim3(6, 64), 512, 0, stream>>>(hid, 1536, m2T, 1536, m2b, q_cur, nullptr, 384, 1536, 384, 384);
  // 13. output transpose
  transpose_k<<<dim3(D_/32, N_/32, B_), tb32, 0, stream>>>(q_cur, out, N_, D_);
}

// Round 9
// 432.942 us; speedup vs baseline: 1.2139x; 1.2139x over previous
//
#include <hip/hip_runtime.h>
#include <cstdint>
#include <cstddef>

#define B_ 4
#define N_ 2048
#define D_ 384
#define H_ 8
#define HD_ 48
#define G_ 512
#define K_ 8
#define HID_ 1536
#define FIN_ 515
#define FINP_ 576
#define M_ (B_*N_)
#define QSCALE 0.20823512f   // 48^-0.5 * log2(e)  -> softmax in exp2 domain

typedef unsigned short u16;
typedef __attribute__((ext_vector_type(8))) short bf16x8;
typedef __attribute__((ext_vector_type(4))) float f32x4;

// direct HBM->LDS DMA, 16B per lane, LDS dest = wave-uniform base + lane*16
#define GLOAD16(gp, lp) __builtin_amdgcn_global_load_lds( \
    (const __attribute__((address_space(1))) void*)(gp), \
    (__attribute__((address_space(3))) void*)(lp), 16, 0, 0)

__device__ __forceinline__ u16 f2bf(float x){
  unsigned u = __builtin_bit_cast(unsigned, x);
  unsigned r = (u + 0x7fffu + ((u >> 16) & 1u)) >> 16;
  return (u16)r;
}
__device__ __forceinline__ float bf2f(u16 v){
  unsigned u = ((unsigned)v) << 16;
  return __builtin_bit_cast(float, u);
}
__device__ __forceinline__ float exp2_hw(float x){
  float r;
  asm("v_exp_f32 %0, %1" : "=v"(r) : "v"(x));
  return r;
}
__device__ __forceinline__ float gelu_f(float x){
  return 0.5f*x*(1.f + erff(x*0.70710678118654752f));
}

// ---------------- transpose [B,R,C] -> [B,C,R] (f32) ----------------
__global__ __launch_bounds__(256) void transpose_k(const float* __restrict__ in,
    float* __restrict__ out, int R, int C){
  __shared__ float tile[32][33];
  int b = blockIdx.z;
  int c0 = blockIdx.x<<5, r0 = blockIdx.y<<5;
  const float* ip = in + (size_t)b*R*C;
  float* op = out + (size_t)b*R*C;
  int tx = threadIdx.x, ty = threadIdx.y;
  #pragma unroll
  for (int i = ty; i < 32; i += 8)
    tile[i][tx] = ip[(size_t)(r0+i)*C + c0 + tx];
  __syncthreads();
  #pragma unroll
  for (int i = ty; i < 32; i += 8)
    op[(size_t)(c0+i)*R + r0 + tx] = tile[tx][i];
}

// ---------------- merged weight transpose+convert ----------------
// Np = padded output-row count: rows [Nd, Np) are written as ZEROS (uninit
// workspace may hold NaN; NaN*0=NaN would poison padded-K gemms).
struct WJob { const float* src; u16* dst; int Kd, Nd, Kp, diff, Np, nbx, blk0; };
struct WJobs { WJob j[16]; };

__global__ __launch_bounds__(256) void wtconv_all(WJobs J){
  int b = blockIdx.x, ji = 0;
  #pragma unroll
  for (int i=1;i<16;i++) if (b >= J.j[i].blk0) ji = i;
  WJob jb = J.j[ji];
  int local = b - jb.blk0;
  int bx = local % jb.nbx, by = local / jb.nbx;
  __shared__ float tile[32][33];
  int k0 = bx<<5, n0 = by<<5;
  int tx = threadIdx.x, ty = threadIdx.y;
  #pragma unroll
  for (int i = ty; i < 32; i += 8){
    int k = k0+i, n = n0+tx;
    float v = 0.f;
    if (k < jb.Kd && n < jb.Nd){
      v = jb.src[(size_t)k*jb.Nd + n];
      if (jb.diff) v = jb.src[(size_t)(k+jb.diff)*jb.Nd + n] - v;
    }
    tile[i][tx] = v;
  }
  __syncthreads();
  #pragma unroll
  for (int i = ty; i < 32; i += 8){
    int n = n0+i, k = k0+tx;
    if (n < jb.Np && k < jb.Kp) jb.dst[(size_t)n*jb.Kp + k] = f2bf(tile[tx][i]);
  }
}

// ---------------- weight-product fold: W[n][k] = (pw @ mwt_top)[k][n], bias ----
struct WP { const float *pw, *mwt, *pb, *mb2; u16* W; float* Bo; };
__global__ __launch_bounds__(256) void wprod_k(WP a, WP b){
  WP w = blockIdx.y ? b : a;
  int idx = blockIdx.x*256 + threadIdx.x;
  if (idx >= 385*384) return;
  int n = idx % 384, kk = idx / 384;      // kk: 0..384 (384 = bias row)
  float acc = 0.f;
  if (kk < 384){
    for (int j=0;j<384;j++) acc += w.pw[(size_t)kk*384+j] * w.mwt[(size_t)j*384+n];
    w.W[(size_t)n*768 + kk] = f2bf(acc);
  } else {
    for (int j=0;j<384;j++) acc += w.pb[j] * w.mwt[(size_t)j*384+n];
    w.Bo[n] = acc + w.mb2[n];
  }
}

// ---------------- concat-bias fill ----------------
__global__ __launch_bounds__(256) void biasfill_k(const float* __restrict__ knnb,
    const float* __restrict__ knnxb, float* __restrict__ bws){
  int i = blockIdx.x*256 + threadIdx.x;
  if (i < 2688){
    float v = 0.f;
    if (i >= 1536 && i < 1920) v = knnb[i-1536];
    else if (i >= 2304) v = knnxb[i-2304];
    bws[i] = v;
  }
}

// ---------------- LayerNorm core ----------------
__device__ __forceinline__ void ln_body(const float* xr, const float* g,
    const float* bta, u16* yr, float* sbuf, int t){
  float v0 = xr[t], v1 = xr[t+128], v2 = xr[t+256];
  float s = v0+v1+v2;
  #pragma unroll
  for (int off=32; off>0; off>>=1) s += __shfl_down(s, off, 64);
  int lane = t & 63, w = t >> 6;
  if (lane==0) sbuf[w] = s;
  __syncthreads();
  float mean = (sbuf[0]+sbuf[1]) * (1.f/(float)D_);
  float d0 = v0-mean, d1 = v1-mean, d2 = v2-mean;
  float s2 = d0*d0 + d1*d1 + d2*d2;
  #pragma unroll
  for (int off=32; off>0; off>>=1) s2 += __shfl_down(s2, off, 64);
  __syncthreads();
  if (lane==0) sbuf[w] = s2;
  __syncthreads();
  float inv = rsqrtf((sbuf[0]+sbuf[1])*(1.f/(float)D_) + 1e-5f);
  yr[t]     = f2bf(d0*inv*g[t]     + bta[t]);
  yr[t+128] = f2bf(d1*inv*g[t+128] + bta[t+128]);
  yr[t+256] = f2bf(d2*inv*g[t+256] + bta[t+256]);
}

__global__ __launch_bounds__(128) void ln_bf(const float* __restrict__ x,
    const float* __restrict__ g, const float* __restrict__ bta, u16* __restrict__ y){
  __shared__ float sbuf[2];
  int row = blockIdx.x;
  ln_body(x + (size_t)row*D_, g, bta, y + (size_t)row*D_, sbuf, threadIdx.x);
}

__global__ __launch_bounds__(128) void ln2_bf(const float* __restrict__ x0,
    const float* __restrict__ g0, const float* __restrict__ b0, u16* __restrict__ y0,
    const float* __restrict__ x1, const float* __restrict__ g1,
    const float* __restrict__ b1, u16* __restrict__ y1){
  __shared__ float sbuf[2];
  int row = blockIdx.x;
  if (row < M_)
    ln_body(x0 + (size_t)row*D_, g0, b0, y0 + (size_t)row*D_, sbuf, threadIdx.x);
  else {
    row -= M_;
    ln_body(x1 + (size_t)row*D_, g1, b1, y1 + (size_t)row*D_, sbuf, threadIdx.x);
  }
}

// ---------------- MFMA GEMM, 512 thr, split-K x2 (round-6 + XCD swizzle) ----
// BM=128 BN=64, BK=64 staged (32 per K-group). 8 waves: kg = wv>>2, 2x2 within.
// Staging via global_load_lds (linear LDS dest, XOR swizzle folded into the
// per-lane GLOBAL source slot -- involution, read addressing unchanged).
// Bijective XCD swizzle (m204): each XCD owns a contiguous chunk of the
// row-major block space -> per-XCD A-working-set ~2.3MB fits the 4MB L2
// (default round-robin scatters across all 64 M-rows = 6.3MB, thrashes).
// REQUIRES: Kd multiple of 64, A/W rows fully allocated+zero-padded.
template<int ACT, int OUTBF, int ACCUM, int HASBIAS, int SCALEQ>
__global__ __launch_bounds__(512) void gemm8(const u16* __restrict__ A, int lda,
    const u16* __restrict__ Wt, int ldw, const float* __restrict__ bias,
    float* __restrict__ Cf, u16* __restrict__ Cb, int ldc, int Kd, int Nd, int Npad){
  __shared__ char Lmem[33280];                 // max(192*64*2, 128*65*4)
  u16* As = (u16*)Lmem;                        // [128][64], row 128B = 8 slots
  u16* Bs = As + 128*64;                       // [64][64]
  float* cred = (float*)Lmem;                  // [128][65] f32 (after K-loop)
  const int t = threadIdx.x;
  const int wv = t>>6, l = t&63;
  const int kg = wv>>2, wq = wv&3;
  const int wm = wq&1, wn = wq>>1;
  const int lr = l&15, ls = l>>4;
  // bijective XCD swizzle of the 2D grid (m204 formula)
  int nbx = gridDim.x;
  int nwg = nbx * gridDim.y;
  int bid = blockIdx.y*nbx + blockIdx.x;
  int qc = nwg>>3, rc = nwg&7;
  int xcd = bid&7, sub = bid>>3;
  int swz = (xcd<rc ? xcd*(qc+1) : rc*(qc+1) + (xcd-rc)*qc) + sub;
  const int bm = (swz / nbx)<<7, bn = (swz % nbx)<<6;
  f32x4 z4 = {0.f,0.f,0.f,0.f};
  f32x4 acc[4][2];
  #pragma unroll
  for (int mi=0;mi<4;mi++){ acc[mi][0]=z4; acc[mi][1]=z4; }
  // per-lane source offsets (elements), constant across K-steps
  int ago[2];
  #pragma unroll
  for (int i=0;i<2;i++){
    int g = t + (i<<9);
    int row = g>>3, slot = g&7;
    ago[i] = row*lda + ((slot ^ (row&7))<<3);
  }
  int bgo;
  {
    int row = t>>3, slot = t&7;
    bgo = row*ldw + ((slot ^ (row&7))<<3);
  }
  const u16* Abase = A + (size_t)bm*lda;
  const u16* Bbase = Wt + (size_t)bn*ldw;
  for (int k0=0; k0<Kd; k0+=64){
    #pragma unroll
    for (int i=0;i<2;i++)
      GLOAD16(Abase + k0 + ago[i], (char*)As + ((t + (i<<9))<<4));
    GLOAD16(Bbase + k0 + bgo, (char*)Bs + (t<<4));
    __syncthreads();
    bf16x8 af[4], bfr[2];
    #pragma unroll
    for (int mi=0;mi<4;mi++){
      int row = wm*64 + mi*16 + lr;
      int ss = (kg*4 + ls) ^ (row&7);
      af[mi] = *reinterpret_cast<bf16x8*>((char*)As + row*128 + ss*16);
    }
    #pragma unroll
    for (int ni=0;ni<2;ni++){
      int row = wn*32 + ni*16 + lr;
      int ss = (kg*4 + ls) ^ (row&7);
      bfr[ni] = *reinterpret_cast<bf16x8*>((char*)Bs + row*128 + ss*16);
    }
    #pragma unroll
    for (int mi=0;mi<4;mi++)
      #pragma unroll
      for (int ni=0;ni<2;ni++)
        acc[mi][ni] = __builtin_amdgcn_mfma_f32_16x16x32_bf16(af[mi], bfr[ni], acc[mi][ni], 0,0,0);
    __syncthreads();
  }
  // split-K reduce: group1 -> LDS, group0 adds + epilogue
  if (kg == 1){
    #pragma unroll
    for (int mi=0;mi<4;mi++)
      #pragma unroll
      for (int ni=0;ni<2;ni++)
        #pragma unroll
        for (int r=0;r<4;r++){
          int row = wm*64 + mi*16 + ls*4 + r;
          int col = wn*32 + ni*16 + lr;
          cred[row*65 + col] = acc[mi][ni][r];
        }
  }
  __syncthreads();
  if (kg == 0){
    #pragma unroll
    for (int mi=0;mi<4;mi++){
      #pragma unroll
      for (int ni=0;ni<2;ni++){
        #pragma unroll
        for (int r=0;r<4;r++){
          int rl = wm*64 + mi*16 + ls*4 + r;
          int cl = wn*32 + ni*16 + lr;
          int row = bm + rl, col = bn + cl;
          float v = acc[mi][ni][r] + cred[rl*65 + cl];
          if (col < Nd){
            if (SCALEQ && col < 384) v *= QSCALE;
            if (HASBIAS) v += bias[col];
            if (ACT) v = gelu_f(v);
            if (OUTBF) Cb[(size_t)row*ldc + col] = f2bf(v);
            else if (ACCUM) Cf[(size_t)row*ldc + col] += v;
            else Cf[(size_t)row*ldc + col] = v;
          } else if (OUTBF && col < Npad){
            Cb[(size_t)row*ldc + col] = 0;
          }
        }
      }
    }
  }
}

// ---------------- V^T builder: Vt[bh][48][N], attn-permuted key order -------
// Within each 128-key tile of row d, 16B slot position s holds slot
// u = s ^ (d&15); slot u = [keys 32*(u>>2)+4*(u&3)+0..3 | same+16].
// This makes the attn V-stage a LINEAR global_load_lds while keeping the
// round-1 (conflict-free, verified) LDS read addressing.
__global__ __launch_bounds__(256) void vt_k(const u16* __restrict__ X, int ld,
                                            u16* __restrict__ Vt){
  __shared__ u16 tl[64][72];
  int bh = blockIdx.y, b = bh>>3, h = bh&7;
  int n0 = blockIdx.x<<6;
  #pragma unroll
  for (int i=0;i<2;i++){
    int g = threadIdx.x + (i<<8);
    if (g < 384){
      int r = g/6, c = (g - r*6)*8;
      *reinterpret_cast<float4*>(&tl[r][c]) =
        *reinterpret_cast<const float4*>(X + (size_t)(b*N_ + n0 + r)*ld + h*HD_ + c);
    }
  }
  __syncthreads();
  #pragma unroll
  for (int i=0;i<2;i++){
    int g = threadIdx.x + (i<<8);
    if (g < 384){
      int d = g % 48, sb = g / 48;
      int hf = (n0>>6)&1;
      int kt0 = n0 & ~127;
      size_t rowb = ((size_t)(bh*HD_+d))*N_ + kt0;
      int kA = hf*64 + sb*8;                 // keys kA..kA+7 (two 4-runs)
      ushort4 va, vb;
      va.x = tl[sb*8+0][d]; va.y = tl[sb*8+1][d];
      va.z = tl[sb*8+2][d]; va.w = tl[sb*8+3][d];
      vb.x = tl[sb*8+4][d]; vb.y = tl[sb*8+5][d];
      vb.z = tl[sb*8+6][d]; vb.w = tl[sb*8+7][d];
      int uA = ((kA>>5)<<2) | ((kA>>2)&3);
      int pA = (((uA ^ (d&15)))<<3) + (((kA>>4)&1)<<2);
      int kB = kA + 4;
      int uB = ((kB>>5)<<2) | ((kB>>2)&3);
      int pB = (((uB ^ (d&15)))<<3) + (((kB>>4)&1)<<2);
      *reinterpret_cast<ushort4*>(Vt + rowb + pA) = va;
      *reinterpret_cast<ushort4*>(Vt + rowb + pB) = vb;
    }
  }
}

// ---------------- MFMA flash attention, KVBLK=128, LDS double-buffer --------
// (round-5 version, equal-best 66-70us band; compute-phase bound)
__global__ __launch_bounds__(256) void attn_mfma(const u16* __restrict__ Qp, int ldq,
    const u16* __restrict__ Kp, int ldk, const u16* __restrict__ Vt,
    u16* __restrict__ O, int ldo){
  __shared__ __align__(16) char KVls[2][28672];   // per buf: K 16384B | V 12288B
  const int t = threadIdx.x, wv = t>>6, l = t&63;
  const int lr = l&15, ls = l>>4;
  const int bh = blockIdx.y, bb = bh>>3, h = bh&7;
  const int q0 = blockIdx.x<<6;
  bf16x8 zf = {0,0,0,0,0,0,0,0};
  f32x4 z4 = {0.f,0.f,0.f,0.f};
  const size_t rowQ = ((size_t)(bb*N_ + q0 + wv*16 + lr))*ldq + h*HD_;
  bf16x8 qa0 = *reinterpret_cast<const bf16x8*>(Qp + rowQ + 8*ls);
  bf16x8 qa1 = (ls < 2) ? *reinterpret_cast<const bf16x8*>(Qp + rowQ + 32 + 8*ls) : zf;
  f32x4 oacc[3] = {z4, z4, z4};
  float mrun = -1.0e30f, lrun = 0.f;

  // per-lane global source offsets (elements); LDS dest is linear in granule
  const u16* Kbase = Kp + (size_t)(bb*N_)*ldk + h*HD_;
  const u16* Vbase = Vt + (size_t)bh*HD_*N_;
  int kgo[4];
  #pragma unroll
  for (int i=0;i<4;i++){
    int g = t + (i<<8);
    int key = g>>3, s = g&7;
    kgo[i] = key*ldk + ((s ^ (key&7))<<3);   // source slot for linear dest
  }
  int vgo[3];
  #pragma unroll
  for (int i=0;i<3;i++){
    int g = t + (i<<8);
    int d = g>>4, s = g&15;
    vgo[i] = d*N_ + (s<<3);                  // Vt already attn-permuted
  }

  auto stage = [&](int kt, char* buf){
    const u16* kp = Kbase + (size_t)kt*128*ldk;
    #pragma unroll
    for (int i=0;i<4;i++)
      GLOAD16(kp + kgo[i], buf + ((t + (i<<8))<<4));
    const u16* vp = Vbase + kt*128;
    #pragma unroll
    for (int i=0;i<3;i++)
      GLOAD16(vp + vgo[i], buf + 16384 + ((t + (i<<8))<<4));
  };

  stage(0, KVls[0]);
  for (int kt = 0; kt < N_/128; kt++){
    char* cbuf = KVls[kt&1];
    if (kt+1 < N_/128){
      stage(kt+1, KVls[(kt+1)&1]);
      asm volatile("s_waitcnt vmcnt(7)" ::: "memory");   // tile-kt landed; kt+1 in flight
    } else {
      asm volatile("s_waitcnt vmcnt(0)" ::: "memory");
    }
    __builtin_amdgcn_sched_barrier(0);
    __builtin_amdgcn_s_barrier();
    __builtin_amdgcn_sched_barrier(0);
    // ---- QK^T (swapped): S^T[key][q], key = sub*16+ls*4+r, q = lr ----
    f32x4 S[8];
    __builtin_amdgcn_s_setprio(1);
    #pragma unroll
    for (int sub=0; sub<8; sub++){
      int krow = sub*16 + lr;
      bf16x8 kb0 = *reinterpret_cast<bf16x8*>(cbuf + krow*128 + ((ls ^ (krow&7))<<4));
      bf16x8 kb1 = *reinterpret_cast<bf16x8*>(cbuf + krow*128 + (((4+ls) ^ (krow&7))<<4));
      f32x4 s = __builtin_amdgcn_mfma_f32_16x16x32_bf16(kb0, qa0, z4, 0,0,0);
      S[sub] = __builtin_amdgcn_mfma_f32_16x16x32_bf16(kb1, qa1, s, 0,0,0);
    }
    __builtin_amdgcn_s_setprio(0);
    // ---- online softmax, row fully lane-local ----
    float tm = fmaxf(fmaxf(fmaxf(S[0][0],S[0][1]), fmaxf(S[0][2],S[0][3])),
                     fmaxf(fmaxf(S[1][0],S[1][1]), fmaxf(S[1][2],S[1][3])));
    #pragma unroll
    for (int sub=2;sub<8;sub++)
      tm = fmaxf(tm, fmaxf(fmaxf(S[sub][0],S[sub][1]), fmaxf(S[sub][2],S[sub][3])));
    if (__all(tm - mrun <= 10.f)){
      // defer-max: keep old max, zero cross-lane traffic
      float ps = 0.f;
      #pragma unroll
      for (int sub=0;sub<8;sub++)
        #pragma unroll
        for (int r=0;r<4;r++){
          float p = exp2_hw(S[sub][r]-mrun);
          S[sub][r] = p; ps += p;
        }
      lrun += ps;
    } else {
      float mx = fmaxf(tm, __shfl_xor(tm, 16, 64));
      mx = fmaxf(mx, __shfl_xor(mx, 32, 64));
      float mnew = fmaxf(mrun, mx);
      float al = exp2_hw(mrun - mnew);
      mrun = mnew;
      float ps = 0.f;
      #pragma unroll
      for (int sub=0;sub<8;sub++)
        #pragma unroll
        for (int r=0;r<4;r++){
          float p = exp2_hw(S[sub][r]-mnew);
          S[sub][r] = p; ps += p;
        }
      lrun = lrun*al + ps;
      #pragma unroll
      for (int r=0;r<4;r++){
        float alq = __shfl(al, ls*4 + r, 64);  // al for q = ls*4+r
        oacc[0][r] *= alq; oacc[1][r] *= alq; oacc[2][r] *= alq;
      }
    }
    // ---- pack P A-fragments in-register (no LDS, no cross-lane) ----
    union PU { unsigned u[4]; bf16x8 v; };
    PU pa[4];
    #pragma unroll
    for (int kb=0;kb<4;kb++){
      asm("v_cvt_pk_bf16_f32 %0, %1, %2" : "=v"(pa[kb].u[0]) : "v"(S[2*kb][0]),   "v"(S[2*kb][1]));
      asm("v_cvt_pk_bf16_f32 %0, %1, %2" : "=v"(pa[kb].u[1]) : "v"(S[2*kb][2]),   "v"(S[2*kb][3]));
      asm("v_cvt_pk_bf16_f32 %0, %1, %2" : "=v"(pa[kb].u[2]) : "v"(S[2*kb+1][0]), "v"(S[2*kb+1][1]));
      asm("v_cvt_pk_bf16_f32 %0, %1, %2" : "=v"(pa[kb].u[3]) : "v"(S[2*kb+1][2]), "v"(S[2*kb+1][3]));
    }
    // ---- PV: permuted k-enumeration on the V side, b128 reads ----
    __builtin_amdgcn_s_setprio(1);
    #pragma unroll
    for (int ni=0;ni<3;ni++){
      int d = ni*16 + lr;
      #pragma unroll
      for (int kb=0;kb<4;kb++){
        bf16x8 vb = *reinterpret_cast<bf16x8*>(cbuf + 16384 + d*256 + ((((kb*4+ls) ^ (d&15)))<<4));
        oacc[ni] = __builtin_amdgcn_mfma_f32_16x16x32_bf16(pa[kb].v, vb, oacc[ni], 0,0,0);
      }
    }
    __builtin_amdgcn_s_setprio(0);
    __builtin_amdgcn_sched_barrier(0);
    __builtin_amdgcn_s_barrier();     // WAR: cbuf is re-staged next iteration
    __builtin_amdgcn_sched_barrier(0);
  }
  // final denom: reduce lane-partials across the 4 lanes of each q-row
  float sden = lrun;
  sden += __shfl_xor(sden, 16, 64);
  sden += __shfl_xor(sden, 32, 64);
  #pragma unroll
  for (int r=0;r<4;r++){
    float dq = __shfl(sden, ls*4 + r, 64);     // denom for q = ls*4+r
    float inv = 1.f / dq;
    size_t orow = (size_t)(bb*N_ + q0 + wv*16 + ls*4 + r);
    #pragma unroll
    for (int ni=0;ni<3;ni++)
      O[orow*ldo + h*HD_ + ni*16 + lr] = f2bf(oacc[ni][r] * inv);
  }
}

// ---------------- knn gather + leaky + max over K ----------------
__global__ __launch_bounds__(384) void gather_max_bf(const u16* __restrict__ P, int ldp,
    const u16* __restrict__ Q2, int ldq2, const int* __restrict__ idx,
    u16* __restrict__ out, int ldo){
  int m = blockIdx.x;
  int d = threadIdx.x;
  int b = m >> 11, n = m & (N_-1);
  float q2 = bf2f(Q2[(size_t)m*ldq2 + d]);
  float mx = -3.0e38f;
  #pragma unroll
  for (int k=0;k<K_;k++){
    int j = idx[((b<<3) + k)*N_ + n];
    float val = bf2f(P[(size_t)j*ldp + d]) + q2;
    val = (val >= 0.f) ? val : 0.2f*val;
    mx = fmaxf(mx, val);
  }
  out[(size_t)m*ldo + d] = f2bf(mx);
}

// ---------------- build v_in [M][576] bf16 (zero-padded) ----------------
__global__ __launch_bounds__(256) void build_v(const float* __restrict__ pos,
    const float* __restrict__ gc, u16* __restrict__ v){
  int m = blockIdx.x;
  int b = m >> 11, n = m & (N_-1);
  for (int c = threadIdx.x; c < FINP_; c += 256){
    float val = 0.f;
    if (c < 3) val = pos[(b*3 + c)*N_ + n];
    else if (c < FIN_) val = gc[(b<<9) + (c-3)];
    v[(size_t)m*FINP_ + c] = f2bf(val);
  }
}

extern "C" void kernel_launch(void* const* d_in, const int* in_sizes, int n_in,
                              void* d_out, int out_size, void* d_ws, size_t ws_size,
                              hipStream_t stream){
  const float* q_in   = (const float*)d_in[0];
  const float* in_pos = (const float*)d_in[1];
  const float* guide  = (const float*)d_in[2];
  const float* n1g = (const float*)d_in[3];
  const float* n1b = (const float*)d_in[4];
  const float* qkv_w = (const float*)d_in[5];
  const float* sa_pw = (const float*)d_in[6];
  const float* sa_pb = (const float*)d_in[7];
  const float* nqg = (const float*)d_in[8];
  const float* nqb = (const float*)d_in[9];
  const float* f1w = (const float*)d_in[10];
  const float* f1b = (const float*)d_in[11];
  const float* f2w = (const float*)d_in[12];
  const float* f2b = (const float*)d_in[13];
  const float* nvg = (const float*)d_in[14];
  const float* nvb = (const float*)d_in[15];
  const float* caqw = (const float*)d_in[16];
  const float* cakw = (const float*)d_in[17];
  const float* cavw = (const float*)d_in[18];
  const float* capw = (const float*)d_in[19];
  const float* capb = (const float*)d_in[20];
  const float* n2g = (const float*)d_in[21];
  const float* n2b = (const float*)d_in[22];
  const float* m1w = (const float*)d_in[23];
  const float* m1b = (const float*)d_in[24];
  const float* m2w = (const float*)d_in[25];
  const float* m2b = (const float*)d_in[26];
  const float* knnw = (const float*)d_in[27];
  const float* knnb = (const float*)d_in[28];
  const float* mw = (const float*)d_in[29];
  const float* mb = (const float*)d_in[30];
  const float* knnxw = (const float*)d_in[31];
  const float* knnxb = (const float*)d_in[32];
  const float* mxw = (const float*)d_in[33];
  const float* mxb = (const float*)d_in[34];
  const int* sidx = (const int*)d_in[35];
  const int* cidx = (const int*)d_in[36];
  float* out = (float*)d_out;

  // ---- workspace ----
  const size_t MD = (size_t)M_*D_;
  float* q_cur = (float*)d_ws;
  float* vbuf  = q_cur + MD;
  u16* R     = (u16*)(vbuf + MD);                      // [M][1920]: X1 | Xq+Xv | hid
  u16* nq_bf = R + (size_t)M_*1920;
  u16* nv_bf = nq_bf + MD;
  u16* cc    = nv_bf + MD;                             // [M][768] = [O | knn_f]
  u16* vin   = cc + (size_t)M_*768;
  u16* e2    = vin + (size_t)M_*FINP_;
  u16* Vt    = e2 + (size_t)M_*FINP_;                  // [32][48][2048]
  u16* wb    = Vt + (size_t)32*HD_*N_;
  u16* W1    = wb;  wb += (size_t)1920*384;
  u16* Wq    = wb;  wb += (size_t)768*384;
  u16* Wv    = wb;  wb += (size_t)1152*384;
  u16* Wfold = wb;  wb += (size_t)384*768;
  u16* Wfoldx= wb;  wb += (size_t)384*768;
  u16* f1T   = wb;  wb += (size_t)FINP_*FINP_;
  u16* f2T   = wb;  wb += (size_t)384*FINP_;
  u16* m1T   = wb;  wb += (size_t)1536*384;
  u16* m2T   = wb;  wb += (size_t)384*1536;
  if (((uintptr_t)wb & 3) != 0) wb++;
  float* bias_ws = (float*)wb;                         // 2688 concat + 384 fold + 384 foldx
  const size_t needed = (char*)(bias_ws + 3456) - (char*)d_ws;
  if (ws_size < needed) return;

  u16* X1 = R;
  u16* Xq = R;
  u16* Xv = R + (size_t)M_*768;
  u16* hid = R;

  dim3 tb32(32,8);
  // 1. input transpose
  transpose_k<<<dim3(N_/32, D_/32, B_), tb32, 0, stream>>>(q_in, q_cur, D_, N_);
  // 2. weight conversions (14 jobs)
  WJobs J;
  auto setj = [&](int i, const float* src, u16* dst, int Kd, int Nd, int Kp, int diff, int Np){
    J.j[i].src = src; J.j[i].dst = dst; J.j[i].Kd = Kd; J.j[i].Nd = Nd;
    J.j[i].Kp = Kp; J.j[i].diff = diff; J.j[i].Np = Np;
    J.j[i].nbx = (Kp+31)/32; J.j[i].blk0 = 0;
  };
  setj(0,  qkv_w, W1,                    384, 1152, 384, 0,   1152);
  setj(1,  knnw,  W1 + (size_t)1152*384, 384, 384, 384, 0,    384);
  setj(2,  knnw,  W1 + (size_t)1536*384, 384, 384, 384, 384,  384);
  setj(3,  caqw,  Wq,                    384, 384, 384, 0,    384);
  setj(4,  knnxw, Wq + (size_t)384*384,  384, 384, 384, 384,  384);
  setj(5,  cakw,  Wv,                    384, 384, 384, 0,    384);
  setj(6,  cavw,  Wv + (size_t)384*384,  384, 384, 384, 0,    384);
  setj(7,  knnxw, Wv + (size_t)768*384,  384, 384, 384, 0,    384);
  setj(8,  mw  + (size_t)384*384, Wfold  + 384, 384, 384, 768, 0, 384);   // merge bottom half
  setj(9,  mxw + (size_t)384*384, Wfoldx + 384, 384, 384, 768, 0, 384);   // mergex bottom half
  setj(10, f1w,   f1T, FIN_, FIN_, FINP_, 0, FINP_);   // rows padded to 576 (zeros)
  setj(11, f2w,   f2T, FIN_, 384, FINP_, 0,  384);
  setj(12, m1w,   m1T, 384, 1536, 384, 0,    1536);
  setj(13, m2w,   m2T, 1536, 384, 1536, 0,   384);
  int tot = 0;
  for (int i=0;i<14;i++){ J.j[i].blk0 = tot; tot += J.j[i].nbx * ((J.j[i].Np+31)/32); }
  J.j[14] = J.j[13]; J.j[14].blk0 = 0x7fffffff; J.j[14].nbx = 1;
  J.j[15] = J.j[14];
  wtconv_all<<<tot, tb32, 0, stream>>>(J);
  // folded weights: Wfold[:384] = sa_pw @ mw_top (k-major), bias = mb + sa_pb @ mw_top
  WP wpa = { sa_pw, mw,  sa_pb, mb,  Wfold,  bias_ws + 2688 };
  WP wpb = { capw,  mxw, capb,  mxb, Wfoldx, bias_ws + 3072 };
  wprod_k<<<dim3(578, 2), 256, 0, stream>>>(wpa, wpb);
  biasfill_k<<<11, 256, 0, stream>>>(knnb, knnxb, bias_ws);
  // 3. norm1
  ln_bf<<<M_, 128, 0, stream>>>(q_cur, n1g, n1b, nq_bf);
  // 4. X1 = nq @ [qkv | knnP | knnQ2diff]
  gemm8<0,1,0,1,1><<<dim3(30, 64), 512, 0, stream>>>(nq_bf, 384, W1, 384, bias_ws, nullptr, X1, 1920, 384, 1920, 1920);
  // 5. self attention: O straight into cc[:, :384]
  vt_k<<<dim3(32, 32), 256, 0, stream>>>(X1 + 768, 1920, Vt);
  attn_mfma<<<dim3(32, 32), 256, 0, stream>>>(X1, 1920, X1 + 384, 1920, Vt, cc, 768);
  gather_max_bf<<<M_, 384, 0, stream>>>(X1 + 1152, 1920, X1 + 1536, 1920, sidx, cc + 384, 768);
  // 6. q_cur += [O | knn_f] @ Wfold + bias_fold
  gemm8<0,0,1,1,0><<<dim3(6, 64), 512, 0, stream>>>(cc, 768, Wfold, 768, bias_ws + 2688, q_cur, nullptr, 384, 768, 384, 384);
  // 7. fuse path -> vbuf  (K padded to 576; vin/f1T/f2T/e2 zero-padded)
  build_v<<<M_, 256, 0, stream>>>(in_pos, guide, vin);
  gemm8<1,1,0,1,0><<<dim3(9, 64), 512, 0, stream>>>(vin, FINP_, f1T, FINP_, f1b, nullptr, e2, FINP_, FINP_, FIN_, FINP_);
  gemm8<0,0,0,1,0><<<dim3(6, 64), 512, 0, stream>>>(e2, FINP_, f2T, FINP_, f2b, vbuf, nullptr, 384, FINP_, 384, 384);
  // 8. both norms, one launch
  ln2_bf<<<2*M_, 128, 0, stream>>>(q_cur, nqg, nqb, nq_bf, vbuf, nvg, nvb, nv_bf);
  // 9. cross projections
  gemm8<0,1,0,1,1><<<dim3(12, 64), 512, 0, stream>>>(nq_bf, 384, Wq, 384, bias_ws + 1920, nullptr, Xq, 768, 384, 768, 768);
  gemm8<0,1,0,0,0><<<dim3(18, 64), 512, 0, stream>>>(nv_bf, 384, Wv, 384, nullptr, nullptr, Xv, 1152, 384, 1152, 1152);
  // 10. cross attention
  vt_k<<<dim3(32, 32), 256, 0, stream>>>(Xv + 384, 1152, Vt);
  attn_mfma<<<dim3(32, 32), 256, 0, stream>>>(Xq, 768, Xv, 1152, Vt, cc, 768);
  gather_max_bf<<<M_, 384, 0, stream>>>(Xv + 768, 1152, Xq + 384, 768, cidx, cc + 384, 768);
  // 11. q_cur += [O | knnx_f] @ Wfoldx + biasx
  gemm8<0,0,1,1,0><<<dim3(6, 64), 512, 0, stream>>>(cc, 768, Wfoldx, 768, bias_ws + 3072, q_cur, nullptr, 384, 768, 384, 384);
  // 12. MLP
  ln_bf<<<M_, 128, 0, stream>>>(q_cur, n2g, n2b, nq_bf);
  gemm8<1,1,0,1,0><<<dim3(24, 64), 512, 0, stream>>>(nq_bf, 384, m1T, 384, m1b, nullptr, hid, 1536, 384, 1536, 1536);
  gemm8<0,0,1,1,0><<<dim3(6, 64), 512, 0, stream>>>(hid, 1536, m2T, 1536, m2b, q_cur, nullptr, 384, 1536, 384, 384);
  // 13. output transpose
  transpose_k<<<dim3(D_/32, N_/32, B_), tb32, 0, stream>>>(q_cur, out, N_, D_);
}

// Round 10
// 409.874 us; speedup vs baseline: 1.2822x; 1.0563x over previous
//
#include <hip/hip_runtime.h>
#include <cstdint>
#include <cstddef>

#define B_ 4
#define N_ 2048
#define D_ 384
#define H_ 8
#define HD_ 48
#define G_ 512
#define K_ 8
#define HID_ 1536
#define FIN_ 515
#define FINP_ 576
#define M_ (B_*N_)
#define QSCALE 0.20823512f   // 48^-0.5 * log2(e)  -> softmax in exp2 domain

typedef unsigned short u16;
typedef __attribute__((ext_vector_type(8))) short bf16x8;
typedef __attribute__((ext_vector_type(4))) float f32x4;

// direct HBM->LDS DMA, 16B per lane, LDS dest = wave-uniform base + lane*16
#define GLOAD16(gp, lp) __builtin_amdgcn_global_load_lds( \
    (const __attribute__((address_space(1))) void*)(gp), \
    (__attribute__((address_space(3))) void*)(lp), 16, 0, 0)

__device__ __forceinline__ u16 f2bf(float x){
  unsigned u = __builtin_bit_cast(unsigned, x);
  unsigned r = (u + 0x7fffu + ((u >> 16) & 1u)) >> 16;
  return (u16)r;
}
__device__ __forceinline__ float bf2f(u16 v){
  unsigned u = ((unsigned)v) << 16;
  return __builtin_bit_cast(float, u);
}
__device__ __forceinline__ float exp2_hw(float x){
  float r;
  asm("v_exp_f32 %0, %1" : "=v"(r) : "v"(x));
  return r;
}
__device__ __forceinline__ float gelu_f(float x){
  return 0.5f*x*(1.f + erff(x*0.70710678118654752f));
}

// ---------------- transpose [B,R,C] -> [B,C,R] (f32) ----------------
__global__ __launch_bounds__(256) void transpose_k(const float* __restrict__ in,
    float* __restrict__ out, int R, int C){
  __shared__ float tile[32][33];
  int b = blockIdx.z;
  int c0 = blockIdx.x<<5, r0 = blockIdx.y<<5;
  const float* ip = in + (size_t)b*R*C;
  float* op = out + (size_t)b*R*C;
  int tx = threadIdx.x, ty = threadIdx.y;
  #pragma unroll
  for (int i = ty; i < 32; i += 8)
    tile[i][tx] = ip[(size_t)(r0+i)*C + c0 + tx];
  __syncthreads();
  #pragma unroll
  for (int i = ty; i < 32; i += 8)
    op[(size_t)(c0+i)*R + r0 + tx] = tile[tx][i];
}

// ---------------- merged weight transpose+convert ----------------
// Np = padded output-row count: rows [Nd, Np) are written as ZEROS (uninit
// workspace may hold NaN; NaN*0=NaN would poison padded-K gemms).
struct WJob { const float* src; u16* dst; int Kd, Nd, Kp, diff, Np, nbx, blk0; };
struct WJobs { WJob j[16]; };

__global__ __launch_bounds__(256) void wtconv_all(WJobs J){
  int b = blockIdx.x, ji = 0;
  #pragma unroll
  for (int i=1;i<16;i++) if (b >= J.j[i].blk0) ji = i;
  WJob jb = J.j[ji];
  int local = b - jb.blk0;
  int bx = local % jb.nbx, by = local / jb.nbx;
  __shared__ float tile[32][33];
  int k0 = bx<<5, n0 = by<<5;
  int tx = threadIdx.x, ty = threadIdx.y;
  #pragma unroll
  for (int i = ty; i < 32; i += 8){
    int k = k0+i, n = n0+tx;
    float v = 0.f;
    if (k < jb.Kd && n < jb.Nd){
      v = jb.src[(size_t)k*jb.Nd + n];
      if (jb.diff) v = jb.src[(size_t)(k+jb.diff)*jb.Nd + n] - v;
    }
    tile[i][tx] = v;
  }
  __syncthreads();
  #pragma unroll
  for (int i = ty; i < 32; i += 8){
    int n = n0+i, k = k0+tx;
    if (n < jb.Np && k < jb.Kp) jb.dst[(size_t)n*jb.Kp + k] = f2bf(tile[tx][i]);
  }
}

// ---------------- weight-product fold: W[n][k] = (pw @ mwt_top)[k][n], bias ----
struct WP { const float *pw, *mwt, *pb, *mb2; u16* W; float* Bo; };
__global__ __launch_bounds__(256) void wprod_k(WP a, WP b){
  WP w = blockIdx.y ? b : a;
  int idx = blockIdx.x*256 + threadIdx.x;
  if (idx >= 385*384) return;
  int n = idx % 384, kk = idx / 384;      // kk: 0..384 (384 = bias row)
  float acc = 0.f;
  if (kk < 384){
    for (int j=0;j<384;j++) acc += w.pw[(size_t)kk*384+j] * w.mwt[(size_t)j*384+n];
    w.W[(size_t)n*768 + kk] = f2bf(acc);
  } else {
    for (int j=0;j<384;j++) acc += w.pb[j] * w.mwt[(size_t)j*384+n];
    w.Bo[n] = acc + w.mb2[n];
  }
}

// ---------------- concat-bias fill ----------------
__global__ __launch_bounds__(256) void biasfill_k(const float* __restrict__ knnb,
    const float* __restrict__ knnxb, float* __restrict__ bws){
  int i = blockIdx.x*256 + threadIdx.x;
  if (i < 2688){
    float v = 0.f;
    if (i >= 1536 && i < 1920) v = knnb[i-1536];
    else if (i >= 2304) v = knnxb[i-2304];
    bws[i] = v;
  }
}

// ---------------- LayerNorm core ----------------
__device__ __forceinline__ void ln_body(const float* xr, const float* g,
    const float* bta, u16* yr, float* sbuf, int t){
  float v0 = xr[t], v1 = xr[t+128], v2 = xr[t+256];
  float s = v0+v1+v2;
  #pragma unroll
  for (int off=32; off>0; off>>=1) s += __shfl_down(s, off, 64);
  int lane = t & 63, w = t >> 6;
  if (lane==0) sbuf[w] = s;
  __syncthreads();
  float mean = (sbuf[0]+sbuf[1]) * (1.f/(float)D_);
  float d0 = v0-mean, d1 = v1-mean, d2 = v2-mean;
  float s2 = d0*d0 + d1*d1 + d2*d2;
  #pragma unroll
  for (int off=32; off>0; off>>=1) s2 += __shfl_down(s2, off, 64);
  __syncthreads();
  if (lane==0) sbuf[w] = s2;
  __syncthreads();
  float inv = rsqrtf((sbuf[0]+sbuf[1])*(1.f/(float)D_) + 1e-5f);
  yr[t]     = f2bf(d0*inv*g[t]     + bta[t]);
  yr[t+128] = f2bf(d1*inv*g[t+128] + bta[t+128]);
  yr[t+256] = f2bf(d2*inv*g[t+256] + bta[t+256]);
}

__global__ __launch_bounds__(128) void ln_bf(const float* __restrict__ x,
    const float* __restrict__ g, const float* __restrict__ bta, u16* __restrict__ y){
  __shared__ float sbuf[2];
  int row = blockIdx.x;
  ln_body(x + (size_t)row*D_, g, bta, y + (size_t)row*D_, sbuf, threadIdx.x);
}

__global__ __launch_bounds__(128) void ln2_bf(const float* __restrict__ x0,
    const float* __restrict__ g0, const float* __restrict__ b0, u16* __restrict__ y0,
    const float* __restrict__ x1, const float* __restrict__ g1,
    const float* __restrict__ b1, u16* __restrict__ y1){
  __shared__ float sbuf[2];
  int row = blockIdx.x;
  if (row < M_)
    ln_body(x0 + (size_t)row*D_, g0, b0, y0 + (size_t)row*D_, sbuf, threadIdx.x);
  else {
    row -= M_;
    ln_body(x1 + (size_t)row*D_, g1, b1, y1 + (size_t)row*D_, sbuf, threadIdx.x);
  }
}

// ---------------- MFMA GEMM, 512 thr, split-K x2 (round-6 + XCD swizzle) ----
// BM=128 BN=64, BK=64 staged (32 per K-group). 8 waves: kg = wv>>2, 2x2 within.
// Staging via global_load_lds (linear LDS dest, XOR swizzle folded into the
// per-lane GLOBAL source slot -- involution, read addressing unchanged).
// Bijective XCD swizzle (m204): each XCD owns a contiguous chunk of the
// row-major block space -> per-XCD A-working-set ~2.3MB fits the 4MB L2
// (default round-robin scatters across all 64 M-rows = 6.3MB, thrashes).
// Measured R9: -26.6us total vs no swizzle.
// REQUIRES: Kd multiple of 64, A/W rows fully allocated+zero-padded.
template<int ACT, int OUTBF, int ACCUM, int HASBIAS, int SCALEQ>
__global__ __launch_bounds__(512) void gemm8(const u16* __restrict__ A, int lda,
    const u16* __restrict__ Wt, int ldw, const float* __restrict__ bias,
    float* __restrict__ Cf, u16* __restrict__ Cb, int ldc, int Kd, int Nd, int Npad){
  __shared__ char Lmem[33280];                 // max(192*64*2, 128*65*4)
  u16* As = (u16*)Lmem;                        // [128][64], row 128B = 8 slots
  u16* Bs = As + 128*64;                       // [64][64]
  float* cred = (float*)Lmem;                  // [128][65] f32 (after K-loop)
  const int t = threadIdx.x;
  const int wv = t>>6, l = t&63;
  const int kg = wv>>2, wq = wv&3;
  const int wm = wq&1, wn = wq>>1;
  const int lr = l&15, ls = l>>4;
  // bijective XCD swizzle of the 2D grid (m204 formula)
  int nbx = gridDim.x;
  int nwg = nbx * gridDim.y;
  int bid = blockIdx.y*nbx + blockIdx.x;
  int qc = nwg>>3, rc = nwg&7;
  int xcd = bid&7, sub = bid>>3;
  int swz = (xcd<rc ? xcd*(qc+1) : rc*(qc+1) + (xcd-rc)*qc) + sub;
  const int bm = (swz / nbx)<<7, bn = (swz % nbx)<<6;
  f32x4 z4 = {0.f,0.f,0.f,0.f};
  f32x4 acc[4][2];
  #pragma unroll
  for (int mi=0;mi<4;mi++){ acc[mi][0]=z4; acc[mi][1]=z4; }
  // per-lane source offsets (elements), constant across K-steps
  int ago[2];
  #pragma unroll
  for (int i=0;i<2;i++){
    int g = t + (i<<9);
    int row = g>>3, slot = g&7;
    ago[i] = row*lda + ((slot ^ (row&7))<<3);
  }
  int bgo;
  {
    int row = t>>3, slot = t&7;
    bgo = row*ldw + ((slot ^ (row&7))<<3);
  }
  const u16* Abase = A + (size_t)bm*lda;
  const u16* Bbase = Wt + (size_t)bn*ldw;
  for (int k0=0; k0<Kd; k0+=64){
    #pragma unroll
    for (int i=0;i<2;i++)
      GLOAD16(Abase + k0 + ago[i], (char*)As + ((t + (i<<9))<<4));
    GLOAD16(Bbase + k0 + bgo, (char*)Bs + (t<<4));
    __syncthreads();
    bf16x8 af[4], bfr[2];
    #pragma unroll
    for (int mi=0;mi<4;mi++){
      int row = wm*64 + mi*16 + lr;
      int ss = (kg*4 + ls) ^ (row&7);
      af[mi] = *reinterpret_cast<bf16x8*>((char*)As + row*128 + ss*16);
    }
    #pragma unroll
    for (int ni=0;ni<2;ni++){
      int row = wn*32 + ni*16 + lr;
      int ss = (kg*4 + ls) ^ (row&7);
      bfr[ni] = *reinterpret_cast<bf16x8*>((char*)Bs + row*128 + ss*16);
    }
    #pragma unroll
    for (int mi=0;mi<4;mi++)
      #pragma unroll
      for (int ni=0;ni<2;ni++)
        acc[mi][ni] = __builtin_amdgcn_mfma_f32_16x16x32_bf16(af[mi], bfr[ni], acc[mi][ni], 0,0,0);
    __syncthreads();
  }
  // split-K reduce: group1 -> LDS, group0 adds + epilogue
  if (kg == 1){
    #pragma unroll
    for (int mi=0;mi<4;mi++)
      #pragma unroll
      for (int ni=0;ni<2;ni++)
        #pragma unroll
        for (int r=0;r<4;r++){
          int row = wm*64 + mi*16 + ls*4 + r;
          int col = wn*32 + ni*16 + lr;
          cred[row*65 + col] = acc[mi][ni][r];
        }
  }
  __syncthreads();
  if (kg == 0){
    #pragma unroll
    for (int mi=0;mi<4;mi++){
      #pragma unroll
      for (int ni=0;ni<2;ni++){
        #pragma unroll
        for (int r=0;r<4;r++){
          int rl = wm*64 + mi*16 + ls*4 + r;
          int cl = wn*32 + ni*16 + lr;
          int row = bm + rl, col = bn + cl;
          float v = acc[mi][ni][r] + cred[rl*65 + cl];
          if (col < Nd){
            if (SCALEQ && col < 384) v *= QSCALE;
            if (HASBIAS) v += bias[col];
            if (ACT) v = gelu_f(v);
            if (OUTBF) Cb[(size_t)row*ldc + col] = f2bf(v);
            else if (ACCUM) Cf[(size_t)row*ldc + col] += v;
            else Cf[(size_t)row*ldc + col] = v;
          } else if (OUTBF && col < Npad){
            Cb[(size_t)row*ldc + col] = 0;
          }
        }
      }
    }
  }
}

// ---------------- V^T builder: Vt[bh][48][N], attn-permuted key order -------
// Within each 128-key tile of row d, 16B slot position s holds slot
// u = s ^ (d&15); slot u = [keys 32*(u>>2)+4*(u&3)+0..3 | same+16].
// This makes the attn V-stage a LINEAR global_load_lds while keeping the
// round-1 (conflict-free, verified) LDS read addressing.
__global__ __launch_bounds__(256) void vt_k(const u16* __restrict__ X, int ld,
                                            u16* __restrict__ Vt){
  __shared__ u16 tl[64][72];
  int bh = blockIdx.y, b = bh>>3, h = bh&7;
  int n0 = blockIdx.x<<6;
  #pragma unroll
  for (int i=0;i<2;i++){
    int g = threadIdx.x + (i<<8);
    if (g < 384){
      int r = g/6, c = (g - r*6)*8;
      *reinterpret_cast<float4*>(&tl[r][c]) =
        *reinterpret_cast<const float4*>(X + (size_t)(b*N_ + n0 + r)*ld + h*HD_ + c);
    }
  }
  __syncthreads();
  #pragma unroll
  for (int i=0;i<2;i++){
    int g = threadIdx.x + (i<<8);
    if (g < 384){
      int d = g % 48, sb = g / 48;
      int hf = (n0>>6)&1;
      int kt0 = n0 & ~127;
      size_t rowb = ((size_t)(bh*HD_+d))*N_ + kt0;
      int kA = hf*64 + sb*8;                 // keys kA..kA+7 (two 4-runs)
      ushort4 va, vb;
      va.x = tl[sb*8+0][d]; va.y = tl[sb*8+1][d];
      va.z = tl[sb*8+2][d]; va.w = tl[sb*8+3][d];
      vb.x = tl[sb*8+4][d]; vb.y = tl[sb*8+5][d];
      vb.z = tl[sb*8+6][d]; vb.w = tl[sb*8+7][d];
      int uA = ((kA>>5)<<2) | ((kA>>2)&3);
      int pA = (((uA ^ (d&15)))<<3) + (((kA>>4)&1)<<2);
      int kB = kA + 4;
      int uB = ((kB>>5)<<2) | ((kB>>2)&3);
      int pB = (((uB ^ (d&15)))<<3) + (((kB>>4)&1)<<2);
      *reinterpret_cast<ushort4*>(Vt + rowb + pA) = va;
      *reinterpret_cast<ushort4*>(Vt + rowb + pB) = vb;
    }
  }
}

// ---------------- MFMA flash attention, 8 waves, QBLK=128, KVBLK=128 --------
// Round-5 compute structure per wave (swapped QK^T, in-register P pack,
// conflict-free reads, DMA staging, dbuf + counted vmcnt), widened to 8 waves
// per block: K/V tile shared by 2x the compute -> FETCH halves, and
// waves/SIMD 2 -> 4 (grid 512 = exactly 2 blocks/CU at 56KiB LDS).
// Staging: K = 2 granules/thread; V = 1 + (t<256 ? 1 : 0) -> waves 0-3 issue
// 4 loads/tile, waves 4-7 issue 3; per-wave-uniform vmcnt(4)/vmcnt(3).
__global__ __launch_bounds__(512) void attn_mfma(const u16* __restrict__ Qp, int ldq,
    const u16* __restrict__ Kp, int ldk, const u16* __restrict__ Vt,
    u16* __restrict__ O, int ldo){
  __shared__ __align__(16) char KVls[2][28672];   // per buf: K 16384B | V 12288B
  const int t = threadIdx.x, wv = t>>6, l = t&63;
  const int lr = l&15, ls = l>>4;
  const int bh = blockIdx.y, bb = bh>>3, h = bh&7;
  const int q0 = blockIdx.x<<7;                   // 128 queries per block
  bf16x8 zf = {0,0,0,0,0,0,0,0};
  f32x4 z4 = {0.f,0.f,0.f,0.f};
  const size_t rowQ = ((size_t)(bb*N_ + q0 + wv*16 + lr))*ldq + h*HD_;
  bf16x8 qa0 = *reinterpret_cast<const bf16x8*>(Qp + rowQ + 8*ls);
  bf16x8 qa1 = (ls < 2) ? *reinterpret_cast<const bf16x8*>(Qp + rowQ + 32 + 8*ls) : zf;
  f32x4 oacc[3] = {z4, z4, z4};
  float mrun = -1.0e30f, lrun = 0.f;

  // per-lane global source offsets (elements); LDS dest is linear in granule
  const u16* Kbase = Kp + (size_t)(bb*N_)*ldk + h*HD_;
  const u16* Vbase = Vt + (size_t)bh*HD_*N_;
  int kgo[2];
  #pragma unroll
  for (int i=0;i<2;i++){
    int g = t + (i<<9);
    int key = g>>3, s = g&7;
    kgo[i] = key*ldk + ((s ^ (key&7))<<3);   // source slot for linear dest
  }
  int vgo[2];
  {
    int d0 = t>>4;
    vgo[0] = d0*N_ + ((t&15)<<3);            // granule t   (d 0..31)
    int d1 = 32 + (t>>4);
    vgo[1] = d1*N_ + ((t&15)<<3);            // granule 512+t (d 32..47, t<256)
  }

  auto stage = [&](int kt, char* buf){
    const u16* kp = Kbase + (size_t)kt*128*ldk;
    #pragma unroll
    for (int i=0;i<2;i++)
      GLOAD16(kp + kgo[i], buf + ((t + (i<<9))<<4));
    const u16* vp = Vbase + kt*128;
    GLOAD16(vp + vgo[0], buf + 16384 + (t<<4));
    if (t < 256)
      GLOAD16(vp + vgo[1], buf + 16384 + ((512 + t)<<4));
  };

  stage(0, KVls[0]);
  for (int kt = 0; kt < N_/128; kt++){
    char* cbuf = KVls[kt&1];
    if (kt+1 < N_/128){
      stage(kt+1, KVls[(kt+1)&1]);
      if (wv < 4) asm volatile("s_waitcnt vmcnt(4)" ::: "memory");
      else        asm volatile("s_waitcnt vmcnt(3)" ::: "memory");
    } else {
      asm volatile("s_waitcnt vmcnt(0)" ::: "memory");
    }
    __builtin_amdgcn_sched_barrier(0);
    __builtin_amdgcn_s_barrier();
    __builtin_amdgcn_sched_barrier(0);
    // ---- QK^T (swapped): S^T[key][q], key = sub*16+ls*4+r, q = lr ----
    f32x4 S[8];
    __builtin_amdgcn_s_setprio(1);
    #pragma unroll
    for (int sub=0; sub<8; sub++){
      int krow = sub*16 + lr;
      bf16x8 kb0 = *reinterpret_cast<bf16x8*>(cbuf + krow*128 + ((ls ^ (krow&7))<<4));
      bf16x8 kb1 = *reinterpret_cast<bf16x8*>(cbuf + krow*128 + (((4+ls) ^ (krow&7))<<4));
      f32x4 s = __builtin_amdgcn_mfma_f32_16x16x32_bf16(kb0, qa0, z4, 0,0,0);
      S[sub] = __builtin_amdgcn_mfma_f32_16x16x32_bf16(kb1, qa1, s, 0,0,0);
    }
    __builtin_amdgcn_s_setprio(0);
    // ---- online softmax, row fully lane-local ----
    float tm = fmaxf(fmaxf(fmaxf(S[0][0],S[0][1]), fmaxf(S[0][2],S[0][3])),
                     fmaxf(fmaxf(S[1][0],S[1][1]), fmaxf(S[1][2],S[1][3])));
    #pragma unroll
    for (int sub=2;sub<8;sub++)
      tm = fmaxf(tm, fmaxf(fmaxf(S[sub][0],S[sub][1]), fmaxf(S[sub][2],S[sub][3])));
    if (__all(tm - mrun <= 10.f)){
      // defer-max: keep old max, zero cross-lane traffic
      float ps = 0.f;
      #pragma unroll
      for (int sub=0;sub<8;sub++)
        #pragma unroll
        for (int r=0;r<4;r++){
          float p = exp2_hw(S[sub][r]-mrun);
          S[sub][r] = p; ps += p;
        }
      lrun += ps;
    } else {
      float mx = fmaxf(tm, __shfl_xor(tm, 16, 64));
      mx = fmaxf(mx, __shfl_xor(mx, 32, 64));
      float mnew = fmaxf(mrun, mx);
      float al = exp2_hw(mrun - mnew);
      mrun = mnew;
      float ps = 0.f;
      #pragma unroll
      for (int sub=0;sub<8;sub++)
        #pragma unroll
        for (int r=0;r<4;r++){
          float p = exp2_hw(S[sub][r]-mnew);
          S[sub][r] = p; ps += p;
        }
      lrun = lrun*al + ps;
      #pragma unroll
      for (int r=0;r<4;r++){
        float alq = __shfl(al, ls*4 + r, 64);  // al for q = ls*4+r
        oacc[0][r] *= alq; oacc[1][r] *= alq; oacc[2][r] *= alq;
      }
    }
    // ---- pack P A-fragments in-register (no LDS, no cross-lane) ----
    union PU { unsigned u[4]; bf16x8 v; };
    PU pa[4];
    #pragma unroll
    for (int kb=0;kb<4;kb++){
      asm("v_cvt_pk_bf16_f32 %0, %1, %2" : "=v"(pa[kb].u[0]) : "v"(S[2*kb][0]),   "v"(S[2*kb][1]));
      asm("v_cvt_pk_bf16_f32 %0, %1, %2" : "=v"(pa[kb].u[1]) : "v"(S[2*kb][2]),   "v"(S[2*kb][3]));
      asm("v_cvt_pk_bf16_f32 %0, %1, %2" : "=v"(pa[kb].u[2]) : "v"(S[2*kb+1][0]), "v"(S[2*kb+1][1]));
      asm("v_cvt_pk_bf16_f32 %0, %1, %2" : "=v"(pa[kb].u[3]) : "v"(S[2*kb+1][2]), "v"(S[2*kb+1][3]));
    }
    // ---- PV: permuted k-enumeration on the V side, b128 reads ----
    __builtin_amdgcn_s_setprio(1);
    #pragma unroll
    for (int ni=0;ni<3;ni++){
      int d = ni*16 + lr;
      #pragma unroll
      for (int kb=0;kb<4;kb++){
        bf16x8 vb = *reinterpret_cast<bf16x8*>(cbuf + 16384 + d*256 + ((((kb*4+ls) ^ (d&15)))<<4));
        oacc[ni] = __builtin_amdgcn_mfma_f32_16x16x32_bf16(pa[kb].v, vb, oacc[ni], 0,0,0);
      }
    }
    __builtin_amdgcn_s_setprio(0);
    __builtin_amdgcn_sched_barrier(0);
    __builtin_amdgcn_s_barrier();     // WAR: cbuf is re-staged next iteration
    __builtin_amdgcn_sched_barrier(0);
  }
  // final denom: reduce lane-partials across the 4 lanes of each q-row
  float sden = lrun;
  sden += __shfl_xor(sden, 16, 64);
  sden += __shfl_xor(sden, 32, 64);
  #pragma unroll
  for (int r=0;r<4;r++){
    float dq = __shfl(sden, ls*4 + r, 64);     // denom for q = ls*4+r
    float inv = 1.f / dq;
    size_t orow = (size_t)(bb*N_ + q0 + wv*16 + ls*4 + r);
    #pragma unroll
    for (int ni=0;ni<3;ni++)
      O[orow*ldo + h*HD_ + ni*16 + lr] = f2bf(oacc[ni][r] * inv);
  }
}

// ---------------- knn gather + leaky + max over K ----------------
__global__ __launch_bounds__(384) void gather_max_bf(const u16* __restrict__ P, int ldp,
    const u16* __restrict__ Q2, int ldq2, const int* __restrict__ idx,
    u16* __restrict__ out, int ldo){
  int m = blockIdx.x;
  int d = threadIdx.x;
  int b = m >> 11, n = m & (N_-1);
  float q2 = bf2f(Q2[(size_t)m*ldq2 + d]);
  float mx = -3.0e38f;
  #pragma unroll
  for (int k=0;k<K_;k++){
    int j = idx[((b<<3) + k)*N_ + n];
    float val = bf2f(P[(size_t)j*ldp + d]) + q2;
    val = (val >= 0.f) ? val : 0.2f*val;
    mx = fmaxf(mx, val);
  }
  out[(size_t)m*ldo + d] = f2bf(mx);
}

// ---------------- build v_in [M][576] bf16 (zero-padded) ----------------
__global__ __launch_bounds__(256) void build_v(const float* __restrict__ pos,
    const float* __restrict__ gc, u16* __restrict__ v){
  int m = blockIdx.x;
  int b = m >> 11, n = m & (N_-1);
  for (int c = threadIdx.x; c < FINP_; c += 256){
    float val = 0.f;
    if (c < 3) val = pos[(b*3 + c)*N_ + n];
    else if (c < FIN_) val = gc[(b<<9) + (c-3)];
    v[(size_t)m*FINP_ + c] = f2bf(val);
  }
}

extern "C" void kernel_launch(void* const* d_in, const int* in_sizes, int n_in,
                              void* d_out, int out_size, void* d_ws, size_t ws_size,
                              hipStream_t stream){
  const float* q_in   = (const float*)d_in[0];
  const float* in_pos = (const float*)d_in[1];
  const float* guide  = (const float*)d_in[2];
  const float* n1g = (const float*)d_in[3];
  const float* n1b = (const float*)d_in[4];
  const float* qkv_w = (const float*)d_in[5];
  const float* sa_pw = (const float*)d_in[6];
  const float* sa_pb = (const float*)d_in[7];
  const float* nqg = (const float*)d_in[8];
  const float* nqb = (const float*)d_in[9];
  const float* f1w = (const float*)d_in[10];
  const float* f1b = (const float*)d_in[11];
  const float* f2w = (const float*)d_in[12];
  const float* f2b = (const float*)d_in[13];
  const float* nvg = (const float*)d_in[14];
  const float* nvb = (const float*)d_in[15];
  const float* caqw = (const float*)d_in[16];
  const float* cakw = (const float*)d_in[17];
  const float* cavw = (const float*)d_in[18];
  const float* capw = (const float*)d_in[19];
  const float* capb = (const float*)d_in[20];
  const float* n2g = (const float*)d_in[21];
  const float* n2b = (const float*)d_in[22];
  const float* m1w = (const float*)d_in[23];
  const float* m1b = (const float*)d_in[24];
  const float* m2w = (const float*)d_in[25];
  const float* m2b = (const float*)d_in[26];
  const float* knnw = (const float*)d_in[27];
  const float* knnb = (const float*)d_in[28];
  const float* mw = (const float*)d_in[29];
  const float* mb = (const float*)d_in[30];
  const float* knnxw = (const float*)d_in[31];
  const float* knnxb = (const float*)d_in[32];
  const float* mxw = (const float*)d_in[33];
  const float* mxb = (const float*)d_in[34];
  const int* sidx = (const int*)d_in[35];
  const int* cidx = (const int*)d_in[36];
  float* out = (float*)d_out;

  // ---- workspace ----
  const size_t MD = (size_t)M_*D_;
  float* q_cur = (float*)d_ws;
  float* vbuf  = q_cur + MD;
  u16* R     = (u16*)(vbuf + MD);                      // [M][1920]: X1 | Xq+Xv | hid
  u16* nq_bf = R + (size_t)M_*1920;
  u16* nv_bf = nq_bf + MD;
  u16* cc    = nv_bf + MD;                             // [M][768] = [O | knn_f]
  u16* vin   = cc + (size_t)M_*768;
  u16* e2    = vin + (size_t)M_*FINP_;
  u16* Vt    = e2 + (size_t)M_*FINP_;                  // [32][48][2048]
  u16* wb    = Vt + (size_t)32*HD_*N_;
  u16* W1    = wb;  wb += (size_t)1920*384;
  u16* Wq    = wb;  wb += (size_t)768*384;
  u16* Wv    = wb;  wb += (size_t)1152*384;
  u16* Wfold = wb;  wb += (size_t)384*768;
  u16* Wfoldx= wb;  wb += (size_t)384*768;
  u16* f1T   = wb;  wb += (size_t)FINP_*FINP_;
  u16* f2T   = wb;  wb += (size_t)384*FINP_;
  u16* m1T   = wb;  wb += (size_t)1536*384;
  u16* m2T   = wb;  wb += (size_t)384*1536;
  if (((uintptr_t)wb & 3) != 0) wb++;
  float* bias_ws = (float*)wb;                         // 2688 concat + 384 fold + 384 foldx
  const size_t needed = (char*)(bias_ws + 3456) - (char*)d_ws;
  if (ws_size < needed) return;

  u16* X1 = R;
  u16* Xq = R;
  u16* Xv = R + (size_t)M_*768;
  u16* hid = R;

  dim3 tb32(32,8);
  // 1. input transpose
  transpose_k<<<dim3(N_/32, D_/32, B_), tb32, 0, stream>>>(q_in, q_cur, D_, N_);
  // 2. weight conversions (14 jobs)
  WJobs J;
  auto setj = [&](int i, const float* src, u16* dst, int Kd, int Nd, int Kp, int diff, int Np){
    J.j[i].src = src; J.j[i].dst = dst; J.j[i].Kd = Kd; J.j[i].Nd = Nd;
    J.j[i].Kp = Kp; J.j[i].diff = diff; J.j[i].Np = Np;
    J.j[i].nbx = (Kp+31)/32; J.j[i].blk0 = 0;
  };
  setj(0,  qkv_w, W1,                    384, 1152, 384, 0,   1152);
  setj(1,  knnw,  W1 + (size_t)1152*384, 384, 384, 384, 0,    384);
  setj(2,  knnw,  W1 + (size_t)1536*384, 384, 384, 384, 384,  384);
  setj(3,  caqw,  Wq,                    384, 384, 384, 0,    384);
  setj(4,  knnxw, Wq + (size_t)384*384,  384, 384, 384, 384,  384);
  setj(5,  cakw,  Wv,                    384, 384, 384, 0,    384);
  setj(6,  cavw,  Wv + (size_t)384*384,  384, 384, 384, 0,    384);
  setj(7,  knnxw, Wv + (size_t)768*384,  384, 384, 384, 0,    384);
  setj(8,  mw  + (size_t)384*384, Wfold  + 384, 384, 384, 768, 0, 384);   // merge bottom half
  setj(9,  mxw + (size_t)384*384, Wfoldx + 384, 384, 384, 768, 0, 384);   // mergex bottom half
  setj(10, f1w,   f1T, FIN_, FIN_, FINP_, 0, FINP_);   // rows padded to 576 (zeros)
  setj(11, f2w,   f2T, FIN_, 384, FINP_, 0,  384);
  setj(12, m1w,   m1T, 384, 1536, 384, 0,    1536);
  setj(13, m2w,   m2T, 1536, 384, 1536, 0,   384);
  int tot = 0;
  for (int i=0;i<14;i++){ J.j[i].blk0 = tot; tot += J.j[i].nbx * ((J.j[i].Np+31)/32); }
  J.j[14] = J.j[13]; J.j[14].blk0 = 0x7fffffff; J.j[14].nbx = 1;
  J.j[15] = J.j[14];
  wtconv_all<<<tot, tb32, 0, stream>>>(J);
  // folded weights: Wfold[:384] = sa_pw @ mw_top (k-major), bias = mb + sa_pb @ mw_top
  WP wpa = { sa_pw, mw,  sa_pb, mb,  Wfold,  bias_ws + 2688 };
  WP wpb = { capw,  mxw, capb,  mxb, Wfoldx, bias_ws + 3072 };
  wprod_k<<<dim3(578, 2), 256, 0, stream>>>(wpa, wpb);
  biasfill_k<<<11, 256, 0, stream>>>(knnb, knnxb, bias_ws);
  // 3. norm1
  ln_bf<<<M_, 128, 0, stream>>>(q_cur, n1g, n1b, nq_bf);
  // 4. X1 = nq @ [qkv | knnP | knnQ2diff]
  gemm8<0,1,0,1,1><<<dim3(30, 64), 512, 0, stream>>>(nq_bf, 384, W1, 384, bias_ws, nullptr, X1, 1920, 384, 1920, 1920);
  // 5. self attention: O straight into cc[:, :384]
  vt_k<<<dim3(32, 32), 256, 0, stream>>>(X1 + 768, 1920, Vt);
  attn_mfma<<<dim3(N_/128, 32), 512, 0, stream>>>(X1, 1920, X1 + 384, 1920, Vt, cc, 768);
  gather_max_bf<<<M_, 384, 0, stream>>>(X1 + 1152, 1920, X1 + 1536, 1920, sidx, cc + 384, 768);
  // 6. q_cur += [O | knn_f] @ Wfold + bias_fold
  gemm8<0,0,1,1,0><<<dim3(6, 64), 512, 0, stream>>>(cc, 768, Wfold, 768, bias_ws + 2688, q_cur, nullptr, 384, 768, 384, 384);
  // 7. fuse path -> vbuf  (K padded to 576; vin/f1T/f2T/e2 zero-padded)
  build_v<<<M_, 256, 0, stream>>>(in_pos, guide, vin);
  gemm8<1,1,0,1,0><<<dim3(9, 64), 512, 0, stream>>>(vin, FINP_, f1T, FINP_, f1b, nullptr, e2, FINP_, FINP_, FIN_, FINP_);
  gemm8<0,0,0,1,0><<<dim3(6, 64), 512, 0, stream>>>(e2, FINP_, f2T, FINP_, f2b, vbuf, nullptr, 384, FINP_, 384, 384);
  // 8. both norms, one launch
  ln2_bf<<<2*M_, 128, 0, stream>>>(q_cur, nqg, nqb, nq_bf, vbuf, nvg, nvb, nv_bf);
  // 9. cross projections
  gemm8<0,1,0,1,1><<<dim3(12, 64), 512, 0, stream>>>(nq_bf, 384, Wq, 384, bias_ws + 1920, nullptr, Xq, 768, 384, 768, 768);
  gemm8<0,1,0,0,0><<<dim3(18, 64), 512, 0, stream>>>(nv_bf, 384, Wv, 384, nullptr, nullptr, Xv, 1152, 384, 1152, 1152);
  // 10. cross attention
  vt_k<<<dim3(32, 32), 256, 0, stream>>>(Xv + 384, 1152, Vt);
  attn_mfma<<<dim3(N_/128, 32), 512, 0, stream>>>(Xq, 768, Xv, 1152, Vt, cc, 768);
  gather_max_bf<<<M_, 384, 0, stream>>>(Xv + 768, 1152, Xq + 384, 768, cidx, cc + 384, 768);
  // 11. q_cur += [O | knnx_f] @ Wfoldx + biasx
  gemm8<0,0,1,1,0><<<dim3(6, 64), 512, 0, stream>>>(cc, 768, Wfoldx, 768, bias_ws + 3072, q_cur, nullptr, 384, 768, 384, 384);
  // 12. MLP
  ln_bf<<<M_, 128, 0, stream>>>(q_cur, n2g, n2b, nq_bf);
  gemm8<1,1,0,1,0><<<dim3(24, 64), 512, 0, stream>>>(nq_bf, 384, m1T, 384, m1b, nullptr, hid, 1536, 384, 1536, 1536);
  gemm8<0,0,1,1,0><<<dim3(6, 64), 512, 0, stream>>>(hid, 1536, m2T, 1536, m2b, q_cur, nullptr, 384, 1536, 384, 384);
  // 13. output transpose
  transpose_k<<<dim3(D_/32, N_/32, B_), tb32, 0, stream>>>(q_cur, out, N_, D_);
}

// Round 11
// 402.105 us; speedup vs baseline: 1.3070x; 1.0193x over previous
//
#include <hip/hip_runtime.h>
#include <cstdint>
#include <cstddef>

#define B_ 4
#define N_ 2048
#define D_ 384
#define H_ 8
#define HD_ 48
#define G_ 512
#define K_ 8
#define HID_ 1536
#define FIN_ 515
#define FINP_ 576
#define M_ (B_*N_)
#define QSCALE 0.20823512f   // 48^-0.5 * log2(e)  -> softmax in exp2 domain

typedef unsigned short u16;
typedef __attribute__((ext_vector_type(8))) short bf16x8;
typedef __attribute__((ext_vector_type(4))) float f32x4;

// direct HBM->LDS DMA, 16B per lane, LDS dest = wave-uniform base + lane*16
#define GLOAD16(gp, lp) __builtin_amdgcn_global_load_lds( \
    (const __attribute__((address_space(1))) void*)(gp), \
    (__attribute__((address_space(3))) void*)(lp), 16, 0, 0)

__device__ __forceinline__ u16 f2bf(float x){
  unsigned u = __builtin_bit_cast(unsigned, x);
  unsigned r = (u + 0x7fffu + ((u >> 16) & 1u)) >> 16;
  return (u16)r;
}
__device__ __forceinline__ float bf2f(u16 v){
  unsigned u = ((unsigned)v) << 16;
  return __builtin_bit_cast(float, u);
}
__device__ __forceinline__ float exp2_hw(float x){
  float r;
  asm("v_exp_f32 %0, %1" : "=v"(r) : "v"(x));
  return r;
}
__device__ __forceinline__ float gelu_f(float x){
  return 0.5f*x*(1.f + erff(x*0.70710678118654752f));
}

// ---------------- transpose [B,R,C] -> [B,C,R] (f32) ----------------
__global__ __launch_bounds__(256) void transpose_k(const float* __restrict__ in,
    float* __restrict__ out, int R, int C){
  __shared__ float tile[32][33];
  int b = blockIdx.z;
  int c0 = blockIdx.x<<5, r0 = blockIdx.y<<5;
  const float* ip = in + (size_t)b*R*C;
  float* op = out + (size_t)b*R*C;
  int tx = threadIdx.x, ty = threadIdx.y;
  #pragma unroll
  for (int i = ty; i < 32; i += 8)
    tile[i][tx] = ip[(size_t)(r0+i)*C + c0 + tx];
  __syncthreads();
  #pragma unroll
  for (int i = ty; i < 32; i += 8)
    op[(size_t)(c0+i)*R + r0 + tx] = tile[tx][i];
}

// ---------------- merged weight transpose+convert ----------------
// Np = padded output-row count: rows [Nd, Np) are written as ZEROS (uninit
// workspace may hold NaN; NaN*0=NaN would poison padded-K gemms).
struct WJob { const float* src; u16* dst; int Kd, Nd, Kp, diff, Np, nbx, blk0; };
struct WJobs { WJob j[16]; };

__global__ __launch_bounds__(256) void wtconv_all(WJobs J){
  int b = blockIdx.x, ji = 0;
  #pragma unroll
  for (int i=1;i<16;i++) if (b >= J.j[i].blk0) ji = i;
  WJob jb = J.j[ji];
  int local = b - jb.blk0;
  int bx = local % jb.nbx, by = local / jb.nbx;
  __shared__ float tile[32][33];
  int k0 = bx<<5, n0 = by<<5;
  int tx = threadIdx.x, ty = threadIdx.y;
  #pragma unroll
  for (int i = ty; i < 32; i += 8){
    int k = k0+i, n = n0+tx;
    float v = 0.f;
    if (k < jb.Kd && n < jb.Nd){
      v = jb.src[(size_t)k*jb.Nd + n];
      if (jb.diff) v = jb.src[(size_t)(k+jb.diff)*jb.Nd + n] - v;
    }
    tile[i][tx] = v;
  }
  __syncthreads();
  #pragma unroll
  for (int i = ty; i < 32; i += 8){
    int n = n0+i, k = k0+tx;
    if (n < jb.Np && k < jb.Kp) jb.dst[(size_t)n*jb.Kp + k] = f2bf(tile[tx][i]);
  }
}

// ---------------- weight-product fold: W[n][k] = (pw @ mwt_top)[k][n], bias ----
struct WP { const float *pw, *mwt, *pb, *mb2; u16* W; float* Bo; };
__global__ __launch_bounds__(256) void wprod_k(WP a, WP b){
  WP w = blockIdx.y ? b : a;
  int idx = blockIdx.x*256 + threadIdx.x;
  if (idx >= 385*384) return;
  int n = idx % 384, kk = idx / 384;      // kk: 0..384 (384 = bias row)
  float acc = 0.f;
  if (kk < 384){
    for (int j=0;j<384;j++) acc += w.pw[(size_t)kk*384+j] * w.mwt[(size_t)j*384+n];
    w.W[(size_t)n*768 + kk] = f2bf(acc);
  } else {
    for (int j=0;j<384;j++) acc += w.pb[j] * w.mwt[(size_t)j*384+n];
    w.Bo[n] = acc + w.mb2[n];
  }
}

// ---------------- concat-bias fill ----------------
__global__ __launch_bounds__(256) void biasfill_k(const float* __restrict__ knnb,
    const float* __restrict__ knnxb, float* __restrict__ bws){
  int i = blockIdx.x*256 + threadIdx.x;
  if (i < 2688){
    float v = 0.f;
    if (i >= 1536 && i < 1920) v = knnb[i-1536];
    else if (i >= 2304) v = knnxb[i-2304];
    bws[i] = v;
  }
}

// ---------------- LayerNorm: one WAVE per row (D=384 = 6x64) ----------------
// No LDS, no __syncthreads: 6-value per-lane accumulate + shfl_xor butterfly.
// 512-thread blocks handle 8 rows -> 8x fewer blocks than the 128-thr version.
__device__ __forceinline__ void ln_wave(const float* __restrict__ xr,
    const float* __restrict__ g, const float* __restrict__ bta,
    u16* __restrict__ yr, int lane){
  float v[6];
  #pragma unroll
  for (int j=0;j<6;j++) v[j] = xr[lane + 64*j];
  float s = ((v[0]+v[1]) + (v[2]+v[3])) + (v[4]+v[5]);
  #pragma unroll
  for (int off=32; off>0; off>>=1) s += __shfl_xor(s, off, 64);
  float mean = s * (1.f/(float)D_);
  float s2 = 0.f;
  #pragma unroll
  for (int j=0;j<6;j++){ v[j] -= mean; s2 += v[j]*v[j]; }
  #pragma unroll
  for (int off=32; off>0; off>>=1) s2 += __shfl_xor(s2, off, 64);
  float inv = rsqrtf(s2*(1.f/(float)D_) + 1e-5f);
  #pragma unroll
  for (int j=0;j<6;j++)
    yr[lane + 64*j] = f2bf(v[j]*inv*g[lane+64*j] + bta[lane+64*j]);
}

__global__ __launch_bounds__(512) void ln_bf(const float* __restrict__ x,
    const float* __restrict__ g, const float* __restrict__ bta, u16* __restrict__ y){
  int row = (blockIdx.x<<3) + (threadIdx.x>>6);
  ln_wave(x + (size_t)row*D_, g, bta, y + (size_t)row*D_, threadIdx.x&63);
}

__global__ __launch_bounds__(512) void ln2_bf(const float* __restrict__ x0,
    const float* __restrict__ g0, const float* __restrict__ b0, u16* __restrict__ y0,
    const float* __restrict__ x1, const float* __restrict__ g1,
    const float* __restrict__ b1, u16* __restrict__ y1){
  int row = (blockIdx.x<<3) + (threadIdx.x>>6);
  if (row < M_)
    ln_wave(x0 + (size_t)row*D_, g0, b0, y0 + (size_t)row*D_, threadIdx.x&63);
  else {
    row -= M_;
    ln_wave(x1 + (size_t)row*D_, g1, b1, y1 + (size_t)row*D_, threadIdx.x&63);
  }
}

// ---------------- MFMA GEMM, 512 thr, split-K x2 (round-6 + XCD swizzle) ----
// BM=128 BN=64, BK=64 staged (32 per K-group). 8 waves: kg = wv>>2, 2x2 within.
// Staging via global_load_lds (linear LDS dest, XOR swizzle folded into the
// per-lane GLOBAL source slot -- involution, read addressing unchanged).
// Bijective XCD swizzle (m204): measured R9 -26.6us total vs no swizzle.
// REQUIRES: Kd multiple of 64, A/W rows fully allocated+zero-padded.
template<int ACT, int OUTBF, int ACCUM, int HASBIAS, int SCALEQ>
__global__ __launch_bounds__(512) void gemm8(const u16* __restrict__ A, int lda,
    const u16* __restrict__ Wt, int ldw, const float* __restrict__ bias,
    float* __restrict__ Cf, u16* __restrict__ Cb, int ldc, int Kd, int Nd, int Npad){
  __shared__ char Lmem[33280];                 // max(192*64*2, 128*65*4)
  u16* As = (u16*)Lmem;                        // [128][64], row 128B = 8 slots
  u16* Bs = As + 128*64;                       // [64][64]
  float* cred = (float*)Lmem;                  // [128][65] f32 (after K-loop)
  const int t = threadIdx.x;
  const int wv = t>>6, l = t&63;
  const int kg = wv>>2, wq = wv&3;
  const int wm = wq&1, wn = wq>>1;
  const int lr = l&15, ls = l>>4;
  // bijective XCD swizzle of the 2D grid (m204 formula)
  int nbx = gridDim.x;
  int nwg = nbx * gridDim.y;
  int bid = blockIdx.y*nbx + blockIdx.x;
  int qc = nwg>>3, rc = nwg&7;
  int xcd = bid&7, sub = bid>>3;
  int swz = (xcd<rc ? xcd*(qc+1) : rc*(qc+1) + (xcd-rc)*qc) + sub;
  const int bm = (swz / nbx)<<7, bn = (swz % nbx)<<6;
  f32x4 z4 = {0.f,0.f,0.f,0.f};
  f32x4 acc[4][2];
  #pragma unroll
  for (int mi=0;mi<4;mi++){ acc[mi][0]=z4; acc[mi][1]=z4; }
  // per-lane source offsets (elements), constant across K-steps
  int ago[2];
  #pragma unroll
  for (int i=0;i<2;i++){
    int g = t + (i<<9);
    int row = g>>3, slot = g&7;
    ago[i] = row*lda + ((slot ^ (row&7))<<3);
  }
  int bgo;
  {
    int row = t>>3, slot = t&7;
    bgo = row*ldw + ((slot ^ (row&7))<<3);
  }
  const u16* Abase = A + (size_t)bm*lda;
  const u16* Bbase = Wt + (size_t)bn*ldw;
  for (int k0=0; k0<Kd; k0+=64){
    #pragma unroll
    for (int i=0;i<2;i++)
      GLOAD16(Abase + k0 + ago[i], (char*)As + ((t + (i<<9))<<4));
    GLOAD16(Bbase + k0 + bgo, (char*)Bs + (t<<4));
    __syncthreads();
    bf16x8 af[4], bfr[2];
    #pragma unroll
    for (int mi=0;mi<4;mi++){
      int row = wm*64 + mi*16 + lr;
      int ss = (kg*4 + ls) ^ (row&7);
      af[mi] = *reinterpret_cast<bf16x8*>((char*)As + row*128 + ss*16);
    }
    #pragma unroll
    for (int ni=0;ni<2;ni++){
      int row = wn*32 + ni*16 + lr;
      int ss = (kg*4 + ls) ^ (row&7);
      bfr[ni] = *reinterpret_cast<bf16x8*>((char*)Bs + row*128 + ss*16);
    }
    #pragma unroll
    for (int mi=0;mi<4;mi++)
      #pragma unroll
      for (int ni=0;ni<2;ni++)
        acc[mi][ni] = __builtin_amdgcn_mfma_f32_16x16x32_bf16(af[mi], bfr[ni], acc[mi][ni], 0,0,0);
    __syncthreads();
  }
  // split-K reduce: group1 -> LDS, group0 adds + epilogue
  if (kg == 1){
    #pragma unroll
    for (int mi=0;mi<4;mi++)
      #pragma unroll
      for (int ni=0;ni<2;ni++)
        #pragma unroll
        for (int r=0;r<4;r++){
          int row = wm*64 + mi*16 + ls*4 + r;
          int col = wn*32 + ni*16 + lr;
          cred[row*65 + col] = acc[mi][ni][r];
        }
  }
  __syncthreads();
  if (kg == 0){
    #pragma unroll
    for (int mi=0;mi<4;mi++){
      #pragma unroll
      for (int ni=0;ni<2;ni++){
        #pragma unroll
        for (int r=0;r<4;r++){
          int rl = wm*64 + mi*16 + ls*4 + r;
          int cl = wn*32 + ni*16 + lr;
          int row = bm + rl, col = bn + cl;
          float v = acc[mi][ni][r] + cred[rl*65 + cl];
          if (col < Nd){
            if (SCALEQ && col < 384) v *= QSCALE;
            if (HASBIAS) v += bias[col];
            if (ACT) v = gelu_f(v);
            if (OUTBF) Cb[(size_t)row*ldc + col] = f2bf(v);
            else if (ACCUM) Cf[(size_t)row*ldc + col] += v;
            else Cf[(size_t)row*ldc + col] = v;
          } else if (OUTBF && col < Npad){
            Cb[(size_t)row*ldc + col] = 0;
          }
        }
      }
    }
  }
}

// ---------------- V^T builder: Vt[bh][48][N], attn-permuted key order -------
__global__ __launch_bounds__(256) void vt_k(const u16* __restrict__ X, int ld,
                                            u16* __restrict__ Vt){
  __shared__ u16 tl[64][72];
  int bh = blockIdx.y, b = bh>>3, h = bh&7;
  int n0 = blockIdx.x<<6;
  #pragma unroll
  for (int i=0;i<2;i++){
    int g = threadIdx.x + (i<<8);
    if (g < 384){
      int r = g/6, c = (g - r*6)*8;
      *reinterpret_cast<float4*>(&tl[r][c]) =
        *reinterpret_cast<const float4*>(X + (size_t)(b*N_ + n0 + r)*ld + h*HD_ + c);
    }
  }
  __syncthreads();
  #pragma unroll
  for (int i=0;i<2;i++){
    int g = threadIdx.x + (i<<8);
    if (g < 384){
      int d = g % 48, sb = g / 48;
      int hf = (n0>>6)&1;
      int kt0 = n0 & ~127;
      size_t rowb = ((size_t)(bh*HD_+d))*N_ + kt0;
      int kA = hf*64 + sb*8;                 // keys kA..kA+7 (two 4-runs)
      ushort4 va, vb;
      va.x = tl[sb*8+0][d]; va.y = tl[sb*8+1][d];
      va.z = tl[sb*8+2][d]; va.w = tl[sb*8+3][d];
      vb.x = tl[sb*8+4][d]; vb.y = tl[sb*8+5][d];
      vb.z = tl[sb*8+6][d]; vb.w = tl[sb*8+7][d];
      int uA = ((kA>>5)<<2) | ((kA>>2)&3);
      int pA = (((uA ^ (d&15)))<<3) + (((kA>>4)&1)<<2);
      int kB = kA + 4;
      int uB = ((kB>>5)<<2) | ((kB>>2)&3);
      int pB = (((uB ^ (d&15)))<<3) + (((kB>>4)&1)<<2);
      *reinterpret_cast<ushort4*>(Vt + rowb + pA) = va;
      *reinterpret_cast<ushort4*>(Vt + rowb + pB) = vb;
    }
  }
}

// ---------------- MFMA flash attention, 8 waves, QBLK=128, KVBLK=128 --------
// (round-10 version: 49.6us/dispatch, occupancy 34.6%)
__global__ __launch_bounds__(512) void attn_mfma(const u16* __restrict__ Qp, int ldq,
    const u16* __restrict__ Kp, int ldk, const u16* __restrict__ Vt,
    u16* __restrict__ O, int ldo){
  __shared__ __align__(16) char KVls[2][28672];   // per buf: K 16384B | V 12288B
  const int t = threadIdx.x, wv = t>>6, l = t&63;
  const int lr = l&15, ls = l>>4;
  const int bh = blockIdx.y, bb = bh>>3, h = bh&7;
  const int q0 = blockIdx.x<<7;                   // 128 queries per block
  bf16x8 zf = {0,0,0,0,0,0,0,0};
  f32x4 z4 = {0.f,0.f,0.f,0.f};
  const size_t rowQ = ((size_t)(bb*N_ + q0 + wv*16 + lr))*ldq + h*HD_;
  bf16x8 qa0 = *reinterpret_cast<const bf16x8*>(Qp + rowQ + 8*ls);
  bf16x8 qa1 = (ls < 2) ? *reinterpret_cast<const bf16x8*>(Qp + rowQ + 32 + 8*ls) : zf;
  f32x4 oacc[3] = {z4, z4, z4};
  float mrun = -1.0e30f, lrun = 0.f;

  // per-lane global source offsets (elements); LDS dest is linear in granule
  const u16* Kbase = Kp + (size_t)(bb*N_)*ldk + h*HD_;
  const u16* Vbase = Vt + (size_t)bh*HD_*N_;
  int kgo[2];
  #pragma unroll
  for (int i=0;i<2;i++){
    int g = t + (i<<9);
    int key = g>>3, s = g&7;
    kgo[i] = key*ldk + ((s ^ (key&7))<<3);   // source slot for linear dest
  }
  int vgo[2];
  {
    int d0 = t>>4;
    vgo[0] = d0*N_ + ((t&15)<<3);            // granule t   (d 0..31)
    int d1 = 32 + (t>>4);
    vgo[1] = d1*N_ + ((t&15)<<3);            // granule 512+t (d 32..47, t<256)
  }

  auto stage = [&](int kt, char* buf){
    const u16* kp = Kbase + (size_t)kt*128*ldk;
    #pragma unroll
    for (int i=0;i<2;i++)
      GLOAD16(kp + kgo[i], buf + ((t + (i<<9))<<4));
    const u16* vp = Vbase + kt*128;
    GLOAD16(vp + vgo[0], buf + 16384 + (t<<4));
    if (t < 256)
      GLOAD16(vp + vgo[1], buf + 16384 + ((512 + t)<<4));
  };

  stage(0, KVls[0]);
  for (int kt = 0; kt < N_/128; kt++){
    char* cbuf = KVls[kt&1];
    if (kt+1 < N_/128){
      stage(kt+1, KVls[(kt+1)&1]);
      if (wv < 4) asm volatile("s_waitcnt vmcnt(4)" ::: "memory");
      else        asm volatile("s_waitcnt vmcnt(3)" ::: "memory");
    } else {
      asm volatile("s_waitcnt vmcnt(0)" ::: "memory");
    }
    __builtin_amdgcn_sched_barrier(0);
    __builtin_amdgcn_s_barrier();
    __builtin_amdgcn_sched_barrier(0);
    // ---- QK^T (swapped): S^T[key][q], key = sub*16+ls*4+r, q = lr ----
    f32x4 S[8];
    __builtin_amdgcn_s_setprio(1);
    #pragma unroll
    for (int sub=0; sub<8; sub++){
      int krow = sub*16 + lr;
      bf16x8 kb0 = *reinterpret_cast<bf16x8*>(cbuf + krow*128 + ((ls ^ (krow&7))<<4));
      bf16x8 kb1 = *reinterpret_cast<bf16x8*>(cbuf + krow*128 + (((4+ls) ^ (krow&7))<<4));
      f32x4 s = __builtin_amdgcn_mfma_f32_16x16x32_bf16(kb0, qa0, z4, 0,0,0);
      S[sub] = __builtin_amdgcn_mfma_f32_16x16x32_bf16(kb1, qa1, s, 0,0,0);
    }
    __builtin_amdgcn_s_setprio(0);
    // ---- online softmax, row fully lane-local ----
    float tm = fmaxf(fmaxf(fmaxf(S[0][0],S[0][1]), fmaxf(S[0][2],S[0][3])),
                     fmaxf(fmaxf(S[1][0],S[1][1]), fmaxf(S[1][2],S[1][3])));
    #pragma unroll
    for (int sub=2;sub<8;sub++)
      tm = fmaxf(tm, fmaxf(fmaxf(S[sub][0],S[sub][1]), fmaxf(S[sub][2],S[sub][3])));
    if (__all(tm - mrun <= 10.f)){
      // defer-max: keep old max, zero cross-lane traffic
      float ps = 0.f;
      #pragma unroll
      for (int sub=0;sub<8;sub++)
        #pragma unroll
        for (int r=0;r<4;r++){
          float p = exp2_hw(S[sub][r]-mrun);
          S[sub][r] = p; ps += p;
        }
      lrun += ps;
    } else {
      float mx = fmaxf(tm, __shfl_xor(tm, 16, 64));
      mx = fmaxf(mx, __shfl_xor(mx, 32, 64));
      float mnew = fmaxf(mrun, mx);
      float al = exp2_hw(mrun - mnew);
      mrun = mnew;
      float ps = 0.f;
      #pragma unroll
      for (int sub=0;sub<8;sub++)
        #pragma unroll
        for (int r=0;r<4;r++){
          float p = exp2_hw(S[sub][r]-mnew);
          S[sub][r] = p; ps += p;
        }
      lrun = lrun*al + ps;
      #pragma unroll
      for (int r=0;r<4;r++){
        float alq = __shfl(al, ls*4 + r, 64);  // al for q = ls*4+r
        oacc[0][r] *= alq; oacc[1][r] *= alq; oacc[2][r] *= alq;
      }
    }
    // ---- pack P A-fragments in-register (no LDS, no cross-lane) ----
    union PU { unsigned u[4]; bf16x8 v; };
    PU pa[4];
    #pragma unroll
    for (int kb=0;kb<4;kb++){
      asm("v_cvt_pk_bf16_f32 %0, %1, %2" : "=v"(pa[kb].u[0]) : "v"(S[2*kb][0]),   "v"(S[2*kb][1]));
      asm("v_cvt_pk_bf16_f32 %0, %1, %2" : "=v"(pa[kb].u[1]) : "v"(S[2*kb][2]),   "v"(S[2*kb][3]));
      asm("v_cvt_pk_bf16_f32 %0, %1, %2" : "=v"(pa[kb].u[2]) : "v"(S[2*kb+1][0]), "v"(S[2*kb+1][1]));
      asm("v_cvt_pk_bf16_f32 %0, %1, %2" : "=v"(pa[kb].u[3]) : "v"(S[2*kb+1][2]), "v"(S[2*kb+1][3]));
    }
    // ---- PV: permuted k-enumeration on the V side, b128 reads ----
    __builtin_amdgcn_s_setprio(1);
    #pragma unroll
    for (int ni=0;ni<3;ni++){
      int d = ni*16 + lr;
      #pragma unroll
      for (int kb=0;kb<4;kb++){
        bf16x8 vb = *reinterpret_cast<bf16x8*>(cbuf + 16384 + d*256 + ((((kb*4+ls) ^ (d&15)))<<4));
        oacc[ni] = __builtin_amdgcn_mfma_f32_16x16x32_bf16(pa[kb].v, vb, oacc[ni], 0,0,0);
      }
    }
    __builtin_amdgcn_s_setprio(0);
    __builtin_amdgcn_sched_barrier(0);
    __builtin_amdgcn_s_barrier();     // WAR: cbuf is re-staged next iteration
    __builtin_amdgcn_sched_barrier(0);
  }
  // final denom: reduce lane-partials across the 4 lanes of each q-row
  float sden = lrun;
  sden += __shfl_xor(sden, 16, 64);
  sden += __shfl_xor(sden, 32, 64);
  #pragma unroll
  for (int r=0;r<4;r++){
    float dq = __shfl(sden, ls*4 + r, 64);     // denom for q = ls*4+r
    float inv = 1.f / dq;
    size_t orow = (size_t)(bb*N_ + q0 + wv*16 + ls*4 + r);
    #pragma unroll
    for (int ni=0;ni<3;ni++)
      O[orow*ldo + h*HD_ + ni*16 + lr] = f2bf(oacc[ni][r] * inv);
  }
}

// ---------------- knn gather + leaky + max over K (4 rows/block) ------------
__global__ __launch_bounds__(384) void gather_max_bf(const u16* __restrict__ P, int ldp,
    const u16* __restrict__ Q2, int ldq2, const int* __restrict__ idx,
    u16* __restrict__ out, int ldo){
  int d = threadIdx.x;
  #pragma unroll
  for (int r=0;r<4;r++){
    int m = (blockIdx.x<<2) + r;
    int b = m >> 11, n = m & (N_-1);
    float q2 = bf2f(Q2[(size_t)m*ldq2 + d]);
    float mx = -3.0e38f;
    #pragma unroll
    for (int k=0;k<K_;k++){
      int j = idx[((b<<3) + k)*N_ + n];
      float val = bf2f(P[(size_t)j*ldp + d]) + q2;
      val = (val >= 0.f) ? val : 0.2f*val;
      mx = fmaxf(mx, val);
    }
    out[(size_t)m*ldo + d] = f2bf(mx);
  }
}

// ---------------- build v_in [M][576] bf16 (zero-padded, 4 rows/block) ------
__global__ __launch_bounds__(256) void build_v(const float* __restrict__ pos,
    const float* __restrict__ gc, u16* __restrict__ v){
  #pragma unroll
  for (int r=0;r<4;r++){
    int m = (blockIdx.x<<2) + r;
    int b = m >> 11, n = m & (N_-1);
    for (int c = threadIdx.x; c < FINP_; c += 256){
      float val = 0.f;
      if (c < 3) val = pos[(b*3 + c)*N_ + n];
      else if (c < FIN_) val = gc[(b<<9) + (c-3)];
      v[(size_t)m*FINP_ + c] = f2bf(val);
    }
  }
}

extern "C" void kernel_launch(void* const* d_in, const int* in_sizes, int n_in,
                              void* d_out, int out_size, void* d_ws, size_t ws_size,
                              hipStream_t stream){
  const float* q_in   = (const float*)d_in[0];
  const float* in_pos = (const float*)d_in[1];
  const float* guide  = (const float*)d_in[2];
  const float* n1g = (const float*)d_in[3];
  const float* n1b = (const float*)d_in[4];
  const float* qkv_w = (const float*)d_in[5];
  const float* sa_pw = (const float*)d_in[6];
  const float* sa_pb = (const float*)d_in[7];
  const float* nqg = (const float*)d_in[8];
  const float* nqb = (const float*)d_in[9];
  const float* f1w = (const float*)d_in[10];
  const float* f1b = (const float*)d_in[11];
  const float* f2w = (const float*)d_in[12];
  const float* f2b = (const float*)d_in[13];
  const float* nvg = (const float*)d_in[14];
  const float* nvb = (const float*)d_in[15];
  const float* caqw = (const float*)d_in[16];
  const float* cakw = (const float*)d_in[17];
  const float* cavw = (const float*)d_in[18];
  const float* capw = (const float*)d_in[19];
  const float* capb = (const float*)d_in[20];
  const float* n2g = (const float*)d_in[21];
  const float* n2b = (const float*)d_in[22];
  const float* m1w = (const float*)d_in[23];
  const float* m1b = (const float*)d_in[24];
  const float* m2w = (const float*)d_in[25];
  const float* m2b = (const float*)d_in[26];
  const float* knnw = (const float*)d_in[27];
  const float* knnb = (const float*)d_in[28];
  const float* mw = (const float*)d_in[29];
  const float* mb = (const float*)d_in[30];
  const float* knnxw = (const float*)d_in[31];
  const float* knnxb = (const float*)d_in[32];
  const float* mxw = (const float*)d_in[33];
  const float* mxb = (const float*)d_in[34];
  const int* sidx = (const int*)d_in[35];
  const int* cidx = (const int*)d_in[36];
  float* out = (float*)d_out;

  // ---- workspace ----
  const size_t MD = (size_t)M_*D_;
  float* q_cur = (float*)d_ws;
  float* vbuf  = q_cur + MD;
  u16* R     = (u16*)(vbuf + MD);                      // [M][1920]: X1 | Xq+Xv | hid
  u16* nq_bf = R + (size_t)M_*1920;
  u16* nv_bf = nq_bf + MD;
  u16* cc    = nv_bf + MD;                             // [M][768] = [O | knn_f]
  u16* vin   = cc + (size_t)M_*768;
  u16* e2    = vin + (size_t)M_*FINP_;
  u16* Vt    = e2 + (size_t)M_*FINP_;                  // [32][48][2048]
  u16* wb    = Vt + (size_t)32*HD_*N_;
  u16* W1    = wb;  wb += (size_t)1920*384;
  u16* Wq    = wb;  wb += (size_t)768*384;
  u16* Wv    = wb;  wb += (size_t)1152*384;
  u16* Wfold = wb;  wb += (size_t)384*768;
  u16* Wfoldx= wb;  wb += (size_t)384*768;
  u16* f1T   = wb;  wb += (size_t)FINP_*FINP_;
  u16* f2T   = wb;  wb += (size_t)384*FINP_;
  u16* m1T   = wb;  wb += (size_t)1536*384;
  u16* m2T   = wb;  wb += (size_t)384*1536;
  if (((uintptr_t)wb & 3) != 0) wb++;
  float* bias_ws = (float*)wb;                         // 2688 concat + 384 fold + 384 foldx
  const size_t needed = (char*)(bias_ws + 3456) - (char*)d_ws;
  if (ws_size < needed) return;

  u16* X1 = R;
  u16* Xq = R;
  u16* Xv = R + (size_t)M_*768;
  u16* hid = R;

  dim3 tb32(32,8);
  // 1. input transpose
  transpose_k<<<dim3(N_/32, D_/32, B_), tb32, 0, stream>>>(q_in, q_cur, D_, N_);
  // 2. weight conversions (14 jobs)
  WJobs J;
  auto setj = [&](int i, const float* src, u16* dst, int Kd, int Nd, int Kp, int diff, int Np){
    J.j[i].src = src; J.j[i].dst = dst; J.j[i].Kd = Kd; J.j[i].Nd = Nd;
    J.j[i].Kp = Kp; J.j[i].diff = diff; J.j[i].Np = Np;
    J.j[i].nbx = (Kp+31)/32; J.j[i].blk0 = 0;
  };
  setj(0,  qkv_w, W1,                    384, 1152, 384, 0,   1152);
  setj(1,  knnw,  W1 + (size_t)1152*384, 384, 384, 384, 0,    384);
  setj(2,  knnw,  W1 + (size_t)1536*384, 384, 384, 384, 384,  384);
  setj(3,  caqw,  Wq,                    384, 384, 384, 0,    384);
  setj(4,  knnxw, Wq + (size_t)384*384,  384, 384, 384, 384,  384);
  setj(5,  cakw,  Wv,                    384, 384, 384, 0,    384);
  setj(6,  cavw,  Wv + (size_t)384*384,  384, 384, 384, 0,    384);
  setj(7,  knnxw, Wv + (size_t)768*384,  384, 384, 384, 0,    384);
  setj(8,  mw  + (size_t)384*384, Wfold  + 384, 384, 384, 768, 0, 384);   // merge bottom half
  setj(9,  mxw + (size_t)384*384, Wfoldx + 384, 384, 384, 768, 0, 384);   // mergex bottom half
  setj(10, f1w,   f1T, FIN_, FIN_, FINP_, 0, FINP_);   // rows padded to 576 (zeros)
  setj(11, f2w,   f2T, FIN_, 384, FINP_, 0,  384);
  setj(12, m1w,   m1T, 384, 1536, 384, 0,    1536);
  setj(13, m2w,   m2T, 1536, 384, 1536, 0,   384);
  int tot = 0;
  for (int i=0;i<14;i++){ J.j[i].blk0 = tot; tot += J.j[i].nbx * ((J.j[i].Np+31)/32); }
  J.j[14] = J.j[13]; J.j[14].blk0 = 0x7fffffff; J.j[14].nbx = 1;
  J.j[15] = J.j[14];
  wtconv_all<<<tot, tb32, 0, stream>>>(J);
  // folded weights: Wfold[:384] = sa_pw @ mw_top (k-major), bias = mb + sa_pb @ mw_top
  WP wpa = { sa_pw, mw,  sa_pb, mb,  Wfold,  bias_ws + 2688 };
  WP wpb = { capw,  mxw, capb,  mxb, Wfoldx, bias_ws + 3072 };
  wprod_k<<<dim3(578, 2), 256, 0, stream>>>(wpa, wpb);
  biasfill_k<<<11, 256, 0, stream>>>(knnb, knnxb, bias_ws);
  // 3. norm1
  ln_bf<<<M_/8, 512, 0, stream>>>(q_cur, n1g, n1b, nq_bf);
  // 4. X1 = nq @ [qkv | knnP | knnQ2diff]
  gemm8<0,1,0,1,1><<<dim3(30, 64), 512, 0, stream>>>(nq_bf, 384, W1, 384, bias_ws, nullptr, X1, 1920, 384, 1920, 1920);
  // 5. self attention: O straight into cc[:, :384]
  vt_k<<<dim3(32, 32), 256, 0, stream>>>(X1 + 768, 1920, Vt);
  attn_mfma<<<dim3(N_/128, 32), 512, 0, stream>>>(X1, 1920, X1 + 384, 1920, Vt, cc, 768);
  gather_max_bf<<<M_/4, 384, 0, stream>>>(X1 + 1152, 1920, X1 + 1536, 1920, sidx, cc + 384, 768);
  // 6. q_cur += [O | knn_f] @ Wfold + bias_fold
  gemm8<0,0,1,1,0><<<dim3(6, 64), 512, 0, stream>>>(cc, 768, Wfold, 768, bias_ws + 2688, q_cur, nullptr, 384, 768, 384, 384);
  // 7. fuse path -> vbuf  (K padded to 576; vin/f1T/f2T/e2 zero-padded)
  build_v<<<M_/4, 256, 0, stream>>>(in_pos, guide, vin);
  gemm8<1,1,0,1,0><<<dim3(9, 64), 512, 0, stream>>>(vin, FINP_, f1T, FINP_, f1b, nullptr, e2, FINP_, FINP_, FIN_, FINP_);
  gemm8<0,0,0,1,0><<<dim3(6, 64), 512, 0, stream>>>(e2, FINP_, f2T, FINP_, f2b, vbuf, nullptr, 384, FINP_, 384, 384);
  // 8. both norms, one launch
  ln2_bf<<<2*M_/8, 512, 0, stream>>>(q_cur, nqg, nqb, nq_bf, vbuf, nvg, nvb, nv_bf);
  // 9. cross projections
  gemm8<0,1,0,1,1><<<dim3(12, 64), 512, 0, stream>>>(nq_bf, 384, Wq, 384, bias_ws + 1920, nullptr, Xq, 768, 384, 768, 768);
  gemm8<0,1,0,0,0><<<dim3(18, 64), 512, 0, stream>>>(nv_bf, 384, Wv, 384, nullptr, nullptr, Xv, 1152, 384, 1152, 1152);
  // 10. cross attention
  vt_k<<<dim3(32, 32), 256, 0, stream>>>(Xv + 384, 1152, Vt);
  attn_mfma<<<dim3(N_/128, 32), 512, 0, stream>>>(Xq, 768, Xv, 1152, Vt, cc, 768);
  gather_max_bf<<<M_/4, 384, 0, stream>>>(Xv + 768, 1152, Xq + 384, 768, cidx, cc + 384, 768);
  // 11. q_cur += [O | knnx_f] @ Wfoldx + biasx
  gemm8<0,0,1,1,0><<<dim3(6, 64), 512, 0, stream>>>(cc, 768, Wfoldx, 768, bias_ws + 3072, q_cur, nullptr, 384, 768, 384, 384);
  // 12. MLP
  ln_bf<<<M_/8, 512, 0, stream>>>(q_cur, n2g, n2b, nq_bf);
  gemm8<1,1,0,1,0><<<dim3(24, 64), 512, 0, stream>>>(nq_bf, 384, m1T, 384, m1b, nullptr, hid, 1536, 384, 1536, 1536);
  gemm8<0,0,1,1,0><<<dim3(6, 64), 512, 0, stream>>>(hid, 1536, m2T, 1536, m2b, q_cur, nullptr, 384, 1536, 384, 384);
  // 13. output transpose
  transpose_k<<<dim3(D_/32, N_/32, B_), tb32, 0, stream>>>(q_cur, out, N_, D_);
}